// Round 5
// baseline (294.730 us; speedup 1.0000x reference)
//
#include <hip/hip_runtime.h>
#include <cstdint>

// ---------------------------------------------------------------------------
// SelfAttentionBlock: LN1 -> QKV -> MHA -> proj(+res) -> LN2 -> FFN(+res)
// B=8 N=2048 D=384 H=6 DK=64.  bf16 MFMA for all matmuls, fp32 LN/softmax/
// GELU/residuals.  Verified MFMA layouts (16x16x32 / shape family):
//   A[m=lane&15][k=(lane>>4)*8+j]  B[k=(lane>>4)*8+j][n=lane&15]
//   C/D[row=(lane>>4)*4+r][col=lane&15]
// 16x16x16 (_1k): A[m=lane&15][k=(lane>>4)*4+i], C/D same shape family.
// Round 13: attn is at a structural plateau (5 variants 98-101us; raw
// arithmetic shows no pipe >30%; ~580 TF effective).  The real slack is the
// GEMMs: ~190us vs ~70us ideal, because the k-loop is the serial 2-barrier
// structure (compute ~150cy vs exposed ~500-900cy load latency per step).
// This round: double-buffered DMA pipeline for the GEMM k-loop (same
// vmcnt(0)+s_barrier+prefetch pattern already validated in attn).
// attn unchanged from R12.
// ---------------------------------------------------------------------------

typedef __bf16 bf16;
typedef __bf16 bf16x8 __attribute__((ext_vector_type(8)));
typedef __bf16 bf16x4 __attribute__((ext_vector_type(4)));
typedef short s16x4 __attribute__((ext_vector_type(4)));
typedef float floatx4 __attribute__((ext_vector_type(4)));
typedef uint32_t __attribute__((address_space(1))) gu32;
typedef uint32_t __attribute__((address_space(3))) lu32;

#define NN 2048
#define DD 384
#define HH 6
#define DK 64
#define BB 8
#define MM (BB * NN)   // 16384 rows
#define D3 (3 * DD)    // 1152
#define D2 (2 * DD)    // 768
#define CH (3 + DD)    // 387 output channels

// 0.125 * log2(e): folded into stored Q so softmax is p = exp2(q.k)
#define QSCALE 0.18033688011112042f

static __device__ __forceinline__ s16x4 as_s16x4(bf16x4 v) {
    union { bf16x4 b; s16x4 s; } u; u.b = v; return u.s;
}

// ---------------- small utility kernels ----------------

// all four weight casts in one launch
__global__ void cast_all_kernel(const float* __restrict__ w_qkv, const float* __restrict__ w_o,
                                const float* __restrict__ w1, const float* __restrict__ w2,
                                bf16* __restrict__ o_qkv, bf16* __restrict__ o_o,
                                bf16* __restrict__ o_w1, bf16* __restrict__ o_w2) {
    int i = blockIdx.x * 256 + threadIdx.x;   // total 1179648
    if (i < 442368) o_qkv[i] = (bf16)w_qkv[i];
    else if (i < 589824) o_o[i - 442368] = (bf16)w_o[i - 442368];
    else if (i < 884736) o_w1[i - 589824] = (bf16)w1[i - 589824];
    else o_w2[i - 884736] = (bf16)w2[i - 884736];
}

__global__ void coords_kernel(const float* __restrict__ pts, float* __restrict__ out) {
    int i = blockIdx.x * 256 + threadIdx.x;            // 8*3*2048 = 49152 total
    int b = i / (3 * NN), r = i % (3 * NN);
    out[(size_t)b * CH * NN + r] = pts[(size_t)b * CH * NN + r];
}

// points (B, 3+D, N) -> feats (B, N, D), fp32
__global__ void transpose_kernel(const float* __restrict__ pts, float* __restrict__ feats) {
    __shared__ float T[32][33];
    int n0 = blockIdx.x * 32, d0 = blockIdx.y * 32, b = blockIdx.z;
    int tx = threadIdx.x, ty = threadIdx.y;
    const float* src = pts + (size_t)b * CH * NN;
#pragma unroll
    for (int i = 0; i < 4; ++i)
        T[ty + i * 8][tx] = src[(size_t)(3 + d0 + ty + i * 8) * NN + n0 + tx];
    __syncthreads();
    float* dst = feats + (size_t)b * NN * DD;
#pragma unroll
    for (int i = 0; i < 4; ++i)
        dst[(size_t)(n0 + ty + i * 8) * DD + d0 + tx] = T[tx][ty + i * 8];
}

// rows of 384, one wave per row, fp32 in -> bf16 out
__global__ __launch_bounds__(256) void ln_kernel(const float* __restrict__ x,
                                                 const float* __restrict__ g,
                                                 const float* __restrict__ bta,
                                                 bf16* __restrict__ out) {
    int wave = threadIdx.x >> 6, lane = threadIdx.x & 63;
    int row = blockIdx.x * 4 + wave;
    const float* xr = x + (size_t)row * DD;
    float v[6], s = 0.f, sq = 0.f;
#pragma unroll
    for (int i = 0; i < 6; ++i) { v[i] = xr[lane + i * 64]; s += v[i]; sq += v[i] * v[i]; }
#pragma unroll
    for (int o = 1; o < 64; o <<= 1) { s += __shfl_xor(s, o); sq += __shfl_xor(sq, o); }
    float mu = s * (1.f / DD);
    float var = sq * (1.f / DD) - mu * mu;
    float rs = rsqrtf(var + 1e-5f);
    bf16* orow = out + (size_t)row * DD;
#pragma unroll
    for (int i = 0; i < 6; ++i) {
        int d = lane + i * 64;
        orow[d] = (bf16)((v[i] - mu) * rs * g[d] + bta[d]);
    }
}

// ---------------- GEMM: C[M,NC] = A[M,K] * W[NC,K]^T, fused epilogues ----------------
// Tile: 128 rows x TN cols.  TN=128: 4 waves 2x2 of 64x64 (MI=4).
//                            TN=64 : 4 waves stacked, 32x64 each (MI=2).
// Double-buffered DMA k-loop (R13): prologue-stage k=0; per step
// vmcnt(0) -> s_barrier -> issue k+1 DMA -> compute k.  Load latency for
// step k+1 hides under step k's MFMA + the co-resident block.
// MODE 0: QKV  -> bf16 qkv (Q cols pre-scaled by QSCALE), V transposed to vt
// MODE 1: proj -> fp32 x = C + bias + res
// MODE 2: FF1  -> bf16 gelu(C + bias)
// MODE 3: FF2  -> fp32 out[(b,3+c,n)] = C + bias + res   (final transposed store)
template <int NC, int K, int MODE, int TN>
__global__ __launch_bounds__(256, 2)
void gemm_bt(const bf16* __restrict__ A, const bf16* __restrict__ W,
             const float* __restrict__ bias, const float* __restrict__ res,
             bf16* __restrict__ obf, float* __restrict__ of32, bf16* __restrict__ vt) {
    constexpr int MI = (TN == 128) ? 4 : 2;
    constexpr int NSTEP = K / 32;
    __shared__ bf16 As[2][128 * 32];
    __shared__ bf16 Ws[2][TN * 32];
    const int t = threadIdx.x;
    const int wave = t >> 6, lane = t & 63;
    const int m0 = blockIdx.x * 128, n0 = blockIdx.y * TN;
    const int wm = (TN == 128) ? (wave >> 1) * 64 : wave * 32;
    const int wn = (TN == 128) ? (wave & 1) * 64 : 0;
    const int lr = lane & 15, quad = lane >> 4;
    const int sr = t >> 2, sc = (t & 3) * 8;

    floatx4 acc[MI][4];
#pragma unroll
    for (int mi = 0; mi < MI; ++mi)
#pragma unroll
        for (int ni = 0; ni < 4; ++ni) {
            floatx4 z = {0.f, 0.f, 0.f, 0.f};
            acc[mi][ni] = z;
        }

    // async global->LDS staging, 16B/lane; LDS offset == 16*t (lane*16-contiguous)
    auto stage = [&](int k0, int bsel) {
#pragma unroll
        for (int i = 0; i < 2; ++i) {
            const int r = i * 64 + sr;
            __builtin_amdgcn_global_load_lds(
                (const gu32*)&A[(size_t)(m0 + r) * K + k0 + sc],
                (lu32*)&As[bsel][r * 32 + sc], 16, 0, 0);
        }
#pragma unroll
        for (int i = 0; i < TN / 64; ++i) {
            const int r = i * 64 + sr;
            __builtin_amdgcn_global_load_lds(
                (const gu32*)&W[(size_t)(n0 + r) * K + k0 + sc],
                (lu32*)&Ws[bsel][r * 32 + sc], 16, 0, 0);
        }
    };

    stage(0, 0);   // prologue: k-step 0 in flight

    for (int ks = 0; ks < NSTEP; ++ks) {
        const int cur = ks & 1;
        // own DMA for step ks done; barrier: all waves' slices landed and
        // everyone is finished reading the alternate buffer.
        __builtin_amdgcn_sched_barrier(0);
        asm volatile("s_waitcnt vmcnt(0)" ::: "memory");
        __builtin_amdgcn_s_barrier();
        __builtin_amdgcn_sched_barrier(0);
        if (ks + 1 < NSTEP) stage((ks + 1) * 32, cur ^ 1);   // hide under compute

        bf16x8 af[MI], bfr[4];
#pragma unroll
        for (int mi = 0; mi < MI; ++mi)
            af[mi] = *(const bf16x8*)&As[cur][(wm + mi * 16 + lr) * 32 + quad * 8];
#pragma unroll
        for (int ni = 0; ni < 4; ++ni)
            bfr[ni] = *(const bf16x8*)&Ws[cur][(wn + ni * 16 + lr) * 32 + quad * 8];
#pragma unroll
        for (int mi = 0; mi < MI; ++mi)
#pragma unroll
            for (int ni = 0; ni < 4; ++ni)
                acc[mi][ni] = __builtin_amdgcn_mfma_f32_16x16x32_bf16(af[mi], bfr[ni], acc[mi][ni], 0, 0, 0);
    }

#pragma unroll
    for (int mi = 0; mi < MI; ++mi) {
#pragma unroll
        for (int ni = 0; ni < 4; ++ni) {
            const int r0 = m0 + wm + mi * 16 + quad * 4;  // 4 consecutive rows r0..r0+3
            const int c = n0 + wn + ni * 16 + lr;
            floatx4 v = acc[mi][ni];
            if constexpr (MODE == 0) {
                const int cb = n0 + wn + ni * 16;  // wave-uniform tile col base
                if (cb >= 2 * DD) {
                    // V: store transposed vt[b][h][dk][n], 4 consecutive n -> 8B store
                    const int hh = (c - 2 * DD) >> 6, dk = (c - 2 * DD) & 63;
                    const int b = r0 >> 11, n = r0 & (NN - 1);
                    bf16x4 pk;
#pragma unroll
                    for (int r = 0; r < 4; ++r) pk[r] = (bf16)v[r];
                    *(bf16x4*)&vt[((size_t)(b * HH + hh) * DK + dk) * NN + n] = pk;
                } else {
                    // Q columns (cb < DD) carry the softmax scale; K unscaled.
                    const float sc_q = (cb < DD) ? QSCALE : 1.0f;
#pragma unroll
                    for (int r = 0; r < 4; ++r) obf[(size_t)(r0 + r) * NC + c] = (bf16)(v[r] * sc_q);
                }
            } else if constexpr (MODE == 1) {
#pragma unroll
                for (int r = 0; r < 4; ++r)
                    of32[(size_t)(r0 + r) * NC + c] = v[r] + bias[c] + res[(size_t)(r0 + r) * NC + c];
            } else if constexpr (MODE == 2) {
#pragma unroll
                for (int r = 0; r < 4; ++r) {
                    float u = v[r] + bias[c];
                    obf[(size_t)(r0 + r) * NC + c] = (bf16)(0.5f * u * (1.f + erff(u * 0.70710678118f)));
                }
            } else {  // MODE 3: final residual + transposed store into output
                const int b = r0 >> 11, n = r0 & (NN - 1);
                float o4[4];
#pragma unroll
                for (int r = 0; r < 4; ++r)
                    o4[r] = v[r] + bias[c] + res[(size_t)(r0 + r) * DD + c];
                float4 val = make_float4(o4[0], o4[1], o4[2], o4[3]);
                *(float4*)&of32[((size_t)b * CH + 3 + c) * NN + n] = val;
            }
        }
    }
}

// ---------------- flash attention (round 12: 8 waves x 16 Q rows) ----------
// grid (N/128, B*H), 512 threads = 8 waves; wave owns 16 Q rows (frags in
// registers); K/V j-tiles of 64, double-buffered flat LDS, staged via
// global_load_lds (1 K + 1 V load per thread).  One raw s_barrier + explicit
// vmcnt(0) per tile; DMA for tile t+1 issued before compute of tile t.
// 16B-granule XOR swizzle on the GLOBAL source address; hoisted per-lane
// read offsets.  Per tile: 8-MFMA QK cluster -> batched exp/cvt -> 20-MFMA
// PV cluster (prio 1).
__global__ __launch_bounds__(512, 6)
void attn_kernel(const bf16* __restrict__ qkv, const bf16* __restrict__ vt,
                 bf16* __restrict__ ctx) {
    __shared__ bf16 Ks[2 * 64 * 64];    // K tile  [j][d] (swizzled), x2 buffers
    __shared__ bf16 Vs[2 * 64 * 64];    // V^T tile [d][j] (swizzled), x2 buffers
    const int t = threadIdx.x, wave = t >> 6, lane = t & 63;
    const int lr = lane & 15, quad = lane >> 4, lx = lane & 7;
    const int bh = blockIdx.y, b = bh / HH, h = bh % HH;
    const int q0 = blockIdx.x * 128 + wave * 16;       // this wave's 16 Q rows
    const bf16* qbase = qkv + (size_t)b * NN * D3 + h * DK;          // Q cols (pre-scaled)
    const bf16* kbase = qbase + DD;                                   // K cols
    const bf16* vbase = vt + (size_t)bh * DK * NN;

    // DMA staging geometry: thread t fills physical 16B chunk (t&7) of
    // physical row (t>>3); the content fetched there is LOGICAL chunk
    // (t&7)^(row&7)  -> swizzle applied via the global source address.
    // 512 threads x 16B = 8KB = one full 64x64 bf16 tile per issue.
    const int srow = t >> 3;                           // 0..63
    const int schunk = ((t & 7) ^ (srow & 7)) * 8;     // bf16 elems

    // ---- hoisted per-lane LDS read offsets (bytes) ----
    // K read (nj,ks): row = nj*16+lr (row&7 == lx), phys chunk = (ks*4+quad)^lx
    //   byte addr = koff[ks] + nj*2048      (row stride 128B, chunk 16B)
    const int koff0 = lr * 128 + ((quad) ^ lx) * 16;          // ks=0
    const int koff1 = lr * 128 + ((4 + quad) ^ lx) * 16;      // ks=1
    // V read (nj,nd): row = nd*16+lr, phys chunk = (nj*2+(quad>>1))^lx,
    //   8B half = quad&1;  byte addr = voff[nj] + nd*2048
    const int vq = quad >> 1, vh = (quad & 1) * 8;
    const int voff0 = lr * 128 + ((0 + vq) ^ lx) * 16 + vh;
    const int voff1 = lr * 128 + ((2 + vq) ^ lx) * 16 + vh;
    const int voff2 = lr * 128 + ((4 + vq) ^ lx) * 16 + vh;
    const int voff3 = lr * 128 + ((6 + vq) ^ lx) * 16 + vh;

    // Q frags: wave-private, j-invariant -> registers (used as B-operand:
    // B[k=(lane>>4)*8+j][n=lane&15] with n = q-row, k = head dim)
    bf16x8 aq[2];
#pragma unroll
    for (int ks = 0; ks < 2; ++ks)
        aq[ks] = *(const bf16x8*)&qbase[(size_t)(q0 + lr) * D3 + ks * 32 + quad * 8];

    // ones B-fragment (K=16) for the denominator MFMA
    bf16x4 ones4;
#pragma unroll
    for (int i = 0; i < 4; ++i) ones4[i] = (bf16)1.0f;
    const s16x4 ones_s = as_s16x4(ones4);

    floatx4 o[4], ol;
    {
        floatx4 z = {0.f, 0.f, 0.f, 0.f};
        ol = z;
#pragma unroll
        for (int nd = 0; nd < 4; ++nd) o[nd] = z;
    }

    // issue the 2 DMA loads (16B/lane each) for tile j0 into buffer bsel
    auto stage = [&](int j0, int bsel) {
        __builtin_amdgcn_global_load_lds(
            (const gu32*)&kbase[(size_t)(j0 + srow) * D3 + schunk],
            (lu32*)&Ks[bsel * 4096 + t * 8], 16, 0, 0);
        __builtin_amdgcn_global_load_lds(
            (const gu32*)&vbase[(size_t)srow * NN + j0 + schunk],
            (lu32*)&Vs[bsel * 4096 + t * 8], 16, 0, 0);
    };

    stage(0, 0);   // prologue: tile 0 in flight

    for (int tt = 0; tt < NN / 64; ++tt) {
        const int cur = tt & 1;
        // wait own DMA for tile tt, then barrier: all waves' slices landed,
        // and all waves are done reading the alternate buffer.
        __builtin_amdgcn_sched_barrier(0);
        asm volatile("s_waitcnt vmcnt(0)" ::: "memory");
        __builtin_amdgcn_s_barrier();
        __builtin_amdgcn_sched_barrier(0);
        if (tt + 1 < NN / 64) stage((tt + 1) * 64, cur ^ 1);   // hide under compute

        const char* kbp = (const char*)Ks + cur * 8192;
        const char* vbp = (const char*)Vs + cur * 8192;

        // S^T = K * Q^T (operand swap).  C-layout: lane holds
        // j = nj*16+quad*4+{0..3}, q = lr.
        floatx4 s[4];
#pragma unroll
        for (int nj = 0; nj < 4; ++nj) {
            floatx4 z = {0.f, 0.f, 0.f, 0.f};
            s[nj] = z;
        }
        __builtin_amdgcn_s_setprio(1);
#pragma unroll
        for (int ks = 0; ks < 2; ++ks)
#pragma unroll
            for (int nj = 0; nj < 4; ++nj) {
                bf16x8 bk = *(const bf16x8*)(kbp + (ks ? koff1 : koff0) + nj * 2048);
                s[nj] = __builtin_amdgcn_mfma_f32_16x16x32_bf16(bk, aq[ks], s[nj], 0, 0, 0);
            }
        __builtin_amdgcn_s_setprio(0);

        // p = exp2(s): batch ALL exp+cvt, then one MFMA cluster.
        // Lane's (q=lr, j=nj*16+quad*4+r) values are EXACTLY the 16x16x16
        // A-fragment A[m=lr][k=quad*4+r] for PV step nj -> no LDS round-trip.
        s16x4 ap[4];
#pragma unroll
        for (int nj = 0; nj < 4; ++nj) {
            bf16x4 pk4;
#pragma unroll
            for (int r = 0; r < 4; ++r) pk4[r] = (bf16)exp2f(s[nj][r]);
            ap[nj] = as_s16x4(pk4);
        }

        // O += P V (4 K=16 slices) ; l += P * ones  -- one 20-MFMA cluster
        __builtin_amdgcn_s_setprio(1);
#pragma unroll
        for (int nj = 0; nj < 4; ++nj) {
            const int vo = (nj == 0) ? voff0 : (nj == 1) ? voff1 : (nj == 2) ? voff2 : voff3;
#pragma unroll
            for (int nd = 0; nd < 4; ++nd) {
                s16x4 bv = as_s16x4(*(const bf16x4*)(vbp + vo + nd * 2048));
                o[nd] = __builtin_amdgcn_mfma_f32_16x16x16bf16_1k(ap[nj], bv, o[nd], 0, 0, 0);
            }
            ol = __builtin_amdgcn_mfma_f32_16x16x16bf16_1k(ap[nj], ones_s, ol, 0, 0, 0);
        }
        __builtin_amdgcn_s_setprio(0);
    }

    // finalize: ctx[b,n, h*64+d] = o/l  (bf16); l rows match o rows.
    // C/D rows = q (quad*4+r), cols = d (nd*16+lr).
#pragma unroll
    for (int r = 0; r < 4; ++r) {
        const int n = q0 + quad * 4 + r;
        const float inv = 1.0f / ol[r];
#pragma unroll
        for (int nd = 0; nd < 4; ++nd) {
            const int d = h * DK + nd * 16 + lr;
            ctx[(size_t)(b * NN + n) * DD + d] = (bf16)(o[nd][r] * inv);
        }
    }
}

// ---------------- host launch ----------------

extern "C" void kernel_launch(void* const* d_in, const int* in_sizes, int n_in,
                              void* d_out, int out_size, void* d_ws, size_t ws_size,
                              hipStream_t stream) {
    const float* points = (const float*)d_in[0];
    const float* ln1_g = (const float*)d_in[1];
    const float* ln1_b = (const float*)d_in[2];
    const float* w_qkv = (const float*)d_in[3];
    const float* w_o   = (const float*)d_in[4];
    const float* b_o   = (const float*)d_in[5];
    const float* ln2_g = (const float*)d_in[6];
    const float* ln2_b = (const float*)d_in[7];
    const float* w1    = (const float*)d_in[8];
    const float* b1    = (const float*)d_in[9];
    const float* w2    = (const float*)d_in[10];
    const float* b2    = (const float*)d_in[11];
    float* out = (float*)d_out;

    char* ws = (char*)d_ws;
    size_t off = 0;
    auto alloc = [&](size_t bytes) -> void* {
        void* p = ws + off;
        off += (bytes + 255) & ~(size_t)255;
        return p;
    };
    float* feats = (float*)alloc((size_t)MM * DD * 4);
    float* xbuf  = (float*)alloc((size_t)MM * DD * 4);
    bf16* h1     = (bf16*)alloc((size_t)MM * DD * 2);
    bf16* h2     = (bf16*)alloc((size_t)MM * DD * 2);
    bf16* qkvb   = (bf16*)alloc((size_t)MM * D3 * 2);
    bf16* vtb    = (bf16*)alloc((size_t)BB * HH * DK * NN * 2);
    bf16* ctx    = (bf16*)alloc((size_t)MM * DD * 2);
    bf16* ffh    = (bf16*)alloc((size_t)MM * D2 * 2);
    bf16* wqkv_bf = (bf16*)alloc((size_t)D3 * DD * 2);
    bf16* wo_bf   = (bf16*)alloc((size_t)DD * DD * 2);
    bf16* w1_bf   = (bf16*)alloc((size_t)D2 * DD * 2);
    bf16* w2_bf   = (bf16*)alloc((size_t)DD * D2 * 2);

    cast_all_kernel<<<1179648 / 256, 256, 0, stream>>>(w_qkv, w_o, w1, w2,
                                                       wqkv_bf, wo_bf, w1_bf, w2_bf);
    coords_kernel<<<(BB * 3 * NN) / 256, 256, 0, stream>>>(points, out);
    transpose_kernel<<<dim3(NN / 32, DD / 32, BB), dim3(32, 8), 0, stream>>>(points, feats);
    ln_kernel<<<MM / 4, 256, 0, stream>>>(feats, ln1_g, ln1_b, h1);
    gemm_bt<D3, DD, 0, 128><<<dim3(MM / 128, D3 / 128), 256, 0, stream>>>(
        h1, wqkv_bf, nullptr, nullptr, qkvb, nullptr, vtb);
    attn_kernel<<<dim3(NN / 128, BB * HH), 512, 0, stream>>>(qkvb, vtb, ctx);
    gemm_bt<DD, DD, 1, 64><<<dim3(MM / 128, DD / 64), 256, 0, stream>>>(
        ctx, wo_bf, b_o, feats, nullptr, xbuf, nullptr);
    ln_kernel<<<MM / 4, 256, 0, stream>>>(xbuf, ln2_g, ln2_b, h2);
    gemm_bt<D2, DD, 2, 128><<<dim3(MM / 128, D2 / 128), 256, 0, stream>>>(
        h2, w1_bf, b1, nullptr, ffh, nullptr, nullptr);
    gemm_bt<DD, D2, 3, 64><<<dim3(MM / 128, DD / 64), 256, 0, stream>>>(
        ffh, w2_bf, b2, xbuf, nullptr, out, nullptr);
}

// Round 6
// 292.011 us; speedup vs baseline: 1.0093x; 1.0093x over previous
//
#include <hip/hip_runtime.h>
#include <cstdint>

// ---------------------------------------------------------------------------
// SelfAttentionBlock: LN1 -> QKV -> MHA -> proj(+res) -> LN2 -> FFN(+res)
// B=8 N=2048 D=384 H=6 DK=64.  bf16 MFMA for all matmuls, fp32 LN/softmax/
// GELU/residuals.  Verified MFMA layouts (16x16x32 / shape family):
//   A[m=lane&15][k=(lane>>4)*8+j]  B[k=(lane>>4)*8+j][n=lane&15]
//   C/D[row=(lane>>4)*4+r][col=lane&15]
// 16x16x16 (_1k): A[m=lane&15][k=(lane>>4)*4+i], C/D same shape family.
// Round 14: R13's depth-1 dbuf was NULL -- predicted by learn_hip m218:
// "pipeline-with-drain0 == no pipeline; the gain IS the counted vmcnt".
// This round: TRUE T4.  3 LDS buffers, wait vmcnt(L) (L = one stage's load
// count, newest stage stays in flight), barrier, issue stage k+2, compute k.
// Load latency covered by ~2 compute phases.  Applied to GEMM (vmcnt 4/3)
// and attn (vmcnt 2).  Stage-issue sits after the barrier that proves all
// waves finished reading the target buffer (race-safe, m152 lesson).
// ---------------------------------------------------------------------------

typedef __bf16 bf16;
typedef __bf16 bf16x8 __attribute__((ext_vector_type(8)));
typedef __bf16 bf16x4 __attribute__((ext_vector_type(4)));
typedef short s16x4 __attribute__((ext_vector_type(4)));
typedef float floatx4 __attribute__((ext_vector_type(4)));
typedef uint32_t __attribute__((address_space(1))) gu32;
typedef uint32_t __attribute__((address_space(3))) lu32;

#define NN 2048
#define DD 384
#define HH 6
#define DK 64
#define BB 8
#define MM (BB * NN)   // 16384 rows
#define D3 (3 * DD)    // 1152
#define D2 (2 * DD)    // 768
#define CH (3 + DD)    // 387 output channels

// 0.125 * log2(e): folded into stored Q so softmax is p = exp2(q.k)
#define QSCALE 0.18033688011112042f

static __device__ __forceinline__ s16x4 as_s16x4(bf16x4 v) {
    union { bf16x4 b; s16x4 s; } u; u.b = v; return u.s;
}

// ---------------- small utility kernels ----------------

// all four weight casts in one launch
__global__ void cast_all_kernel(const float* __restrict__ w_qkv, const float* __restrict__ w_o,
                                const float* __restrict__ w1, const float* __restrict__ w2,
                                bf16* __restrict__ o_qkv, bf16* __restrict__ o_o,
                                bf16* __restrict__ o_w1, bf16* __restrict__ o_w2) {
    int i = blockIdx.x * 256 + threadIdx.x;   // total 1179648
    if (i < 442368) o_qkv[i] = (bf16)w_qkv[i];
    else if (i < 589824) o_o[i - 442368] = (bf16)w_o[i - 442368];
    else if (i < 884736) o_w1[i - 589824] = (bf16)w1[i - 589824];
    else o_w2[i - 884736] = (bf16)w2[i - 884736];
}

__global__ void coords_kernel(const float* __restrict__ pts, float* __restrict__ out) {
    int i = blockIdx.x * 256 + threadIdx.x;            // 8*3*2048 = 49152 total
    int b = i / (3 * NN), r = i % (3 * NN);
    out[(size_t)b * CH * NN + r] = pts[(size_t)b * CH * NN + r];
}

// points (B, 3+D, N) -> feats (B, N, D), fp32
__global__ void transpose_kernel(const float* __restrict__ pts, float* __restrict__ feats) {
    __shared__ float T[32][33];
    int n0 = blockIdx.x * 32, d0 = blockIdx.y * 32, b = blockIdx.z;
    int tx = threadIdx.x, ty = threadIdx.y;
    const float* src = pts + (size_t)b * CH * NN;
#pragma unroll
    for (int i = 0; i < 4; ++i)
        T[ty + i * 8][tx] = src[(size_t)(3 + d0 + ty + i * 8) * NN + n0 + tx];
    __syncthreads();
    float* dst = feats + (size_t)b * NN * DD;
#pragma unroll
    for (int i = 0; i < 4; ++i)
        dst[(size_t)(n0 + ty + i * 8) * DD + d0 + tx] = T[tx][ty + i * 8];
}

// rows of 384, one wave per row, fp32 in -> bf16 out
__global__ __launch_bounds__(256) void ln_kernel(const float* __restrict__ x,
                                                 const float* __restrict__ g,
                                                 const float* __restrict__ bta,
                                                 bf16* __restrict__ out) {
    int wave = threadIdx.x >> 6, lane = threadIdx.x & 63;
    int row = blockIdx.x * 4 + wave;
    const float* xr = x + (size_t)row * DD;
    float v[6], s = 0.f, sq = 0.f;
#pragma unroll
    for (int i = 0; i < 6; ++i) { v[i] = xr[lane + i * 64]; s += v[i]; sq += v[i] * v[i]; }
#pragma unroll
    for (int o = 1; o < 64; o <<= 1) { s += __shfl_xor(s, o); sq += __shfl_xor(sq, o); }
    float mu = s * (1.f / DD);
    float var = sq * (1.f / DD) - mu * mu;
    float rs = rsqrtf(var + 1e-5f);
    bf16* orow = out + (size_t)row * DD;
#pragma unroll
    for (int i = 0; i < 6; ++i) {
        int d = lane + i * 64;
        orow[d] = (bf16)((v[i] - mu) * rs * g[d] + bta[d]);
    }
}

// ---------------- GEMM: C[M,NC] = A[M,K] * W[NC,K]^T, fused epilogues ----------------
// Tile: 128 rows x TN cols.  TN=128: 4 waves 2x2 of 64x64 (MI=4).
//                            TN=64 : 4 waves stacked, 32x64 each (MI=2).
// Round 14 k-loop: 3 LDS buffers, counted vmcnt (never drains to 0 in the
// main loop).  Per step k: vmcnt(L) [stage k landed, stage k+1 in flight] ->
// s_barrier -> issue stage k+2 (buffer provably free) -> compute k.
// MODE 0: QKV  -> bf16 qkv (Q cols pre-scaled by QSCALE), V transposed to vt
// MODE 1: proj -> fp32 x = C + bias + res
// MODE 2: FF1  -> bf16 gelu(C + bias)
// MODE 3: FF2  -> fp32 out[(b,3+c,n)] = C + bias + res   (final transposed store)
template <int NC, int K, int MODE, int TN>
__global__ __launch_bounds__(256, 2)
void gemm_bt(const bf16* __restrict__ A, const bf16* __restrict__ W,
             const float* __restrict__ bias, const float* __restrict__ res,
             bf16* __restrict__ obf, float* __restrict__ of32, bf16* __restrict__ vt) {
    constexpr int MI = (TN == 128) ? 4 : 2;
    constexpr int NSTEP = K / 32;
    __shared__ bf16 As[3][128 * 32];
    __shared__ bf16 Ws[3][TN * 32];
    const int t = threadIdx.x;
    const int wave = t >> 6, lane = t & 63;
    const int m0 = blockIdx.x * 128, n0 = blockIdx.y * TN;
    const int wm = (TN == 128) ? (wave >> 1) * 64 : wave * 32;
    const int wn = (TN == 128) ? (wave & 1) * 64 : 0;
    const int lr = lane & 15, quad = lane >> 4;
    const int sr = t >> 2, sc = (t & 3) * 8;

    floatx4 acc[MI][4];
#pragma unroll
    for (int mi = 0; mi < MI; ++mi)
#pragma unroll
        for (int ni = 0; ni < 4; ++ni) {
            floatx4 z = {0.f, 0.f, 0.f, 0.f};
            acc[mi][ni] = z;
        }

    // async global->LDS staging, 16B/lane; LDS offset == 16*t (lane*16-contiguous)
    auto stage = [&](int k0, int bsel) {
#pragma unroll
        for (int i = 0; i < 2; ++i) {
            const int r = i * 64 + sr;
            __builtin_amdgcn_global_load_lds(
                (const gu32*)&A[(size_t)(m0 + r) * K + k0 + sc],
                (lu32*)&As[bsel][r * 32 + sc], 16, 0, 0);
        }
#pragma unroll
        for (int i = 0; i < TN / 64; ++i) {
            const int r = i * 64 + sr;
            __builtin_amdgcn_global_load_lds(
                (const gu32*)&W[(size_t)(n0 + r) * K + k0 + sc],
                (lu32*)&Ws[bsel][r * 32 + sc], 16, 0, 0);
        }
    };

    stage(0, 0);    // prologue: steps 0 and 1 in flight
    stage(32, 1);

    for (int ks = 0; ks < NSTEP; ++ks) {
        const int cur = ks % 3;
        // counted wait: allow the newest stage (k+1, L loads) to stay in
        // flight; guarantees stage k has landed.
        __builtin_amdgcn_sched_barrier(0);
        if constexpr (TN == 128) asm volatile("s_waitcnt vmcnt(4)" ::: "memory");
        else                     asm volatile("s_waitcnt vmcnt(3)" ::: "memory");
        __builtin_amdgcn_s_barrier();
        __builtin_amdgcn_sched_barrier(0);
        // buffer (ks+2)%3 was read by compute(ks-1); barrier above proves all
        // waves are done with it -> safe to overwrite.
        if (ks + 2 < NSTEP) stage((ks + 2) * 32, (ks + 2) % 3);

        bf16x8 af[MI], bfr[4];
#pragma unroll
        for (int mi = 0; mi < MI; ++mi)
            af[mi] = *(const bf16x8*)&As[cur][(wm + mi * 16 + lr) * 32 + quad * 8];
#pragma unroll
        for (int ni = 0; ni < 4; ++ni)
            bfr[ni] = *(const bf16x8*)&Ws[cur][(wn + ni * 16 + lr) * 32 + quad * 8];
#pragma unroll
        for (int mi = 0; mi < MI; ++mi)
#pragma unroll
            for (int ni = 0; ni < 4; ++ni)
                acc[mi][ni] = __builtin_amdgcn_mfma_f32_16x16x32_bf16(af[mi], bfr[ni], acc[mi][ni], 0, 0, 0);
    }

#pragma unroll
    for (int mi = 0; mi < MI; ++mi) {
#pragma unroll
        for (int ni = 0; ni < 4; ++ni) {
            const int r0 = m0 + wm + mi * 16 + quad * 4;  // 4 consecutive rows r0..r0+3
            const int c = n0 + wn + ni * 16 + lr;
            floatx4 v = acc[mi][ni];
            if constexpr (MODE == 0) {
                const int cb = n0 + wn + ni * 16;  // wave-uniform tile col base
                if (cb >= 2 * DD) {
                    // V: store transposed vt[b][h][dk][n], 4 consecutive n -> 8B store
                    const int hh = (c - 2 * DD) >> 6, dk = (c - 2 * DD) & 63;
                    const int b = r0 >> 11, n = r0 & (NN - 1);
                    bf16x4 pk;
#pragma unroll
                    for (int r = 0; r < 4; ++r) pk[r] = (bf16)v[r];
                    *(bf16x4*)&vt[((size_t)(b * HH + hh) * DK + dk) * NN + n] = pk;
                } else {
                    // Q columns (cb < DD) carry the softmax scale; K unscaled.
                    const float sc_q = (cb < DD) ? QSCALE : 1.0f;
#pragma unroll
                    for (int r = 0; r < 4; ++r) obf[(size_t)(r0 + r) * NC + c] = (bf16)(v[r] * sc_q);
                }
            } else if constexpr (MODE == 1) {
#pragma unroll
                for (int r = 0; r < 4; ++r)
                    of32[(size_t)(r0 + r) * NC + c] = v[r] + bias[c] + res[(size_t)(r0 + r) * NC + c];
            } else if constexpr (MODE == 2) {
#pragma unroll
                for (int r = 0; r < 4; ++r) {
                    float u = v[r] + bias[c];
                    obf[(size_t)(r0 + r) * NC + c] = (bf16)(0.5f * u * (1.f + erff(u * 0.70710678118f)));
                }
            } else {  // MODE 3: final residual + transposed store into output
                const int b = r0 >> 11, n = r0 & (NN - 1);
                float o4[4];
#pragma unroll
                for (int r = 0; r < 4; ++r)
                    o4[r] = v[r] + bias[c] + res[(size_t)(r0 + r) * DD + c];
                float4 val = make_float4(o4[0], o4[1], o4[2], o4[3]);
                *(float4*)&of32[((size_t)b * CH + 3 + c) * NN + n] = val;
            }
        }
    }
}

// ---------------- flash attention (round 14: counted-vmcnt 3-buffer) -------
// grid (N/128, B*H), 512 threads = 8 waves; wave owns 16 Q rows (frags in
// registers); K/V j-tiles of 64, TRIPLE-buffered flat LDS, staged via
// global_load_lds (1 K + 1 V load per thread per stage).  Per tile t:
// vmcnt(2) [tile t landed, t+1 in flight] -> s_barrier -> issue stage t+2
// -> compute t.  16B-granule XOR swizzle on the GLOBAL source address;
// hoisted per-lane read offsets; batched exp; prio-1 MFMA clusters.
__global__ __launch_bounds__(512, 6)
void attn_kernel(const bf16* __restrict__ qkv, const bf16* __restrict__ vt,
                 bf16* __restrict__ ctx) {
    __shared__ bf16 Ks[3 * 64 * 64];    // K tile  [j][d] (swizzled), x3 buffers
    __shared__ bf16 Vs[3 * 64 * 64];    // V^T tile [d][j] (swizzled), x3 buffers
    const int t = threadIdx.x, wave = t >> 6, lane = t & 63;
    const int lr = lane & 15, quad = lane >> 4, lx = lane & 7;
    const int bh = blockIdx.y, b = bh / HH, h = bh % HH;
    const int q0 = blockIdx.x * 128 + wave * 16;       // this wave's 16 Q rows
    const bf16* qbase = qkv + (size_t)b * NN * D3 + h * DK;          // Q cols (pre-scaled)
    const bf16* kbase = qbase + DD;                                   // K cols
    const bf16* vbase = vt + (size_t)bh * DK * NN;

    // DMA staging geometry: thread t fills physical 16B chunk (t&7) of
    // physical row (t>>3); the content fetched there is LOGICAL chunk
    // (t&7)^(row&7)  -> swizzle applied via the global source address.
    // 512 threads x 16B = 8KB = one full 64x64 bf16 tile per issue.
    const int srow = t >> 3;                           // 0..63
    const int schunk = ((t & 7) ^ (srow & 7)) * 8;     // bf16 elems

    // ---- hoisted per-lane LDS read offsets (bytes) ----
    // K read (nj,ks): row = nj*16+lr (row&7 == lx), phys chunk = (ks*4+quad)^lx
    //   byte addr = koff[ks] + nj*2048      (row stride 128B, chunk 16B)
    const int koff0 = lr * 128 + ((quad) ^ lx) * 16;          // ks=0
    const int koff1 = lr * 128 + ((4 + quad) ^ lx) * 16;      // ks=1
    // V read (nj,nd): row = nd*16+lr, phys chunk = (nj*2+(quad>>1))^lx,
    //   8B half = quad&1;  byte addr = voff[nj] + nd*2048
    const int vq = quad >> 1, vh = (quad & 1) * 8;
    const int voff0 = lr * 128 + ((0 + vq) ^ lx) * 16 + vh;
    const int voff1 = lr * 128 + ((2 + vq) ^ lx) * 16 + vh;
    const int voff2 = lr * 128 + ((4 + vq) ^ lx) * 16 + vh;
    const int voff3 = lr * 128 + ((6 + vq) ^ lx) * 16 + vh;

    // Q frags: wave-private, j-invariant -> registers (used as B-operand:
    // B[k=(lane>>4)*8+j][n=lane&15] with n = q-row, k = head dim)
    bf16x8 aq[2];
#pragma unroll
    for (int ks = 0; ks < 2; ++ks)
        aq[ks] = *(const bf16x8*)&qbase[(size_t)(q0 + lr) * D3 + ks * 32 + quad * 8];

    // ones B-fragment (K=16) for the denominator MFMA
    bf16x4 ones4;
#pragma unroll
    for (int i = 0; i < 4; ++i) ones4[i] = (bf16)1.0f;
    const s16x4 ones_s = as_s16x4(ones4);

    floatx4 o[4], ol;
    {
        floatx4 z = {0.f, 0.f, 0.f, 0.f};
        ol = z;
#pragma unroll
        for (int nd = 0; nd < 4; ++nd) o[nd] = z;
    }

    // issue the 2 DMA loads (16B/lane each) for tile j0 into buffer bsel
    auto stage = [&](int j0, int bsel) {
        __builtin_amdgcn_global_load_lds(
            (const gu32*)&kbase[(size_t)(j0 + srow) * D3 + schunk],
            (lu32*)&Ks[bsel * 4096 + t * 8], 16, 0, 0);
        __builtin_amdgcn_global_load_lds(
            (const gu32*)&vbase[(size_t)srow * NN + j0 + schunk],
            (lu32*)&Vs[bsel * 4096 + t * 8], 16, 0, 0);
    };

    stage(0, 0);     // prologue: tiles 0 and 1 in flight
    stage(64, 1);

    for (int tt = 0; tt < NN / 64; ++tt) {
        const int cur = tt % 3;
        // counted wait: allow tile t+1's 2 loads to stay in flight; tile t
        // has landed.  Barrier: all waves' slices in, and everyone is done
        // reading buffer (tt+2)%3 (compute tt-1) -> safe to re-stage it.
        __builtin_amdgcn_sched_barrier(0);
        asm volatile("s_waitcnt vmcnt(2)" ::: "memory");
        __builtin_amdgcn_s_barrier();
        __builtin_amdgcn_sched_barrier(0);
        if (tt + 2 < NN / 64) stage((tt + 2) * 64, (tt + 2) % 3);

        const char* kbp = (const char*)Ks + cur * 8192;
        const char* vbp = (const char*)Vs + cur * 8192;

        // S^T = K * Q^T (operand swap).  C-layout: lane holds
        // j = nj*16+quad*4+{0..3}, q = lr.
        floatx4 s[4];
#pragma unroll
        for (int nj = 0; nj < 4; ++nj) {
            floatx4 z = {0.f, 0.f, 0.f, 0.f};
            s[nj] = z;
        }
        __builtin_amdgcn_s_setprio(1);
#pragma unroll
        for (int ks = 0; ks < 2; ++ks)
#pragma unroll
            for (int nj = 0; nj < 4; ++nj) {
                bf16x8 bk = *(const bf16x8*)(kbp + (ks ? koff1 : koff0) + nj * 2048);
                s[nj] = __builtin_amdgcn_mfma_f32_16x16x32_bf16(bk, aq[ks], s[nj], 0, 0, 0);
            }
        __builtin_amdgcn_s_setprio(0);

        // p = exp2(s): batch ALL exp+cvt, then one MFMA cluster.
        // Lane's (q=lr, j=nj*16+quad*4+r) values are EXACTLY the 16x16x16
        // A-fragment A[m=lr][k=quad*4+r] for PV step nj -> no LDS round-trip.
        s16x4 ap[4];
#pragma unroll
        for (int nj = 0; nj < 4; ++nj) {
            bf16x4 pk4;
#pragma unroll
            for (int r = 0; r < 4; ++r) pk4[r] = (bf16)exp2f(s[nj][r]);
            ap[nj] = as_s16x4(pk4);
        }

        // O += P V (4 K=16 slices) ; l += P * ones  -- one 20-MFMA cluster
        __builtin_amdgcn_s_setprio(1);
#pragma unroll
        for (int nj = 0; nj < 4; ++nj) {
            const int vo = (nj == 0) ? voff0 : (nj == 1) ? voff1 : (nj == 2) ? voff2 : voff3;
#pragma unroll
            for (int nd = 0; nd < 4; ++nd) {
                s16x4 bv = as_s16x4(*(const bf16x4*)(vbp + vo + nd * 2048));
                o[nd] = __builtin_amdgcn_mfma_f32_16x16x16bf16_1k(ap[nj], bv, o[nd], 0, 0, 0);
            }
            ol = __builtin_amdgcn_mfma_f32_16x16x16bf16_1k(ap[nj], ones_s, ol, 0, 0, 0);
        }
        __builtin_amdgcn_s_setprio(0);
    }

    // finalize: ctx[b,n, h*64+d] = o/l  (bf16); l rows match o rows.
    // C/D rows = q (quad*4+r), cols = d (nd*16+lr).
#pragma unroll
    for (int r = 0; r < 4; ++r) {
        const int n = q0 + quad * 4 + r;
        const float inv = 1.0f / ol[r];
#pragma unroll
        for (int nd = 0; nd < 4; ++nd) {
            const int d = h * DK + nd * 16 + lr;
            ctx[(size_t)(b * NN + n) * DD + d] = (bf16)(o[nd][r] * inv);
        }
    }
}

// ---------------- host launch ----------------

extern "C" void kernel_launch(void* const* d_in, const int* in_sizes, int n_in,
                              void* d_out, int out_size, void* d_ws, size_t ws_size,
                              hipStream_t stream) {
    const float* points = (const float*)d_in[0];
    const float* ln1_g = (const float*)d_in[1];
    const float* ln1_b = (const float*)d_in[2];
    const float* w_qkv = (const float*)d_in[3];
    const float* w_o   = (const float*)d_in[4];
    const float* b_o   = (const float*)d_in[5];
    const float* ln2_g = (const float*)d_in[6];
    const float* ln2_b = (const float*)d_in[7];
    const float* w1    = (const float*)d_in[8];
    const float* b1    = (const float*)d_in[9];
    const float* w2    = (const float*)d_in[10];
    const float* b2    = (const float*)d_in[11];
    float* out = (float*)d_out;

    char* ws = (char*)d_ws;
    size_t off = 0;
    auto alloc = [&](size_t bytes) -> void* {
        void* p = ws + off;
        off += (bytes + 255) & ~(size_t)255;
        return p;
    };
    float* feats = (float*)alloc((size_t)MM * DD * 4);
    float* xbuf  = (float*)alloc((size_t)MM * DD * 4);
    bf16* h1     = (bf16*)alloc((size_t)MM * DD * 2);
    bf16* h2     = (bf16*)alloc((size_t)MM * DD * 2);
    bf16* qkvb   = (bf16*)alloc((size_t)MM * D3 * 2);
    bf16* vtb    = (bf16*)alloc((size_t)BB * HH * DK * NN * 2);
    bf16* ctx    = (bf16*)alloc((size_t)MM * DD * 2);
    bf16* ffh    = (bf16*)alloc((size_t)MM * D2 * 2);
    bf16* wqkv_bf = (bf16*)alloc((size_t)D3 * DD * 2);
    bf16* wo_bf   = (bf16*)alloc((size_t)DD * DD * 2);
    bf16* w1_bf   = (bf16*)alloc((size_t)D2 * DD * 2);
    bf16* w2_bf   = (bf16*)alloc((size_t)DD * D2 * 2);

    cast_all_kernel<<<1179648 / 256, 256, 0, stream>>>(w_qkv, w_o, w1, w2,
                                                       wqkv_bf, wo_bf, w1_bf, w2_bf);
    coords_kernel<<<(BB * 3 * NN) / 256, 256, 0, stream>>>(points, out);
    transpose_kernel<<<dim3(NN / 32, DD / 32, BB), dim3(32, 8), 0, stream>>>(points, feats);
    ln_kernel<<<MM / 4, 256, 0, stream>>>(feats, ln1_g, ln1_b, h1);
    gemm_bt<D3, DD, 0, 128><<<dim3(MM / 128, D3 / 128), 256, 0, stream>>>(
        h1, wqkv_bf, nullptr, nullptr, qkvb, nullptr, vtb);
    attn_kernel<<<dim3(NN / 128, BB * HH), 512, 0, stream>>>(qkvb, vtb, ctx);
    gemm_bt<DD, DD, 1, 64><<<dim3(MM / 128, DD / 64), 256, 0, stream>>>(
        ctx, wo_bf, b_o, feats, nullptr, xbuf, nullptr);
    ln_kernel<<<MM / 4, 256, 0, stream>>>(xbuf, ln2_g, ln2_b, h2);
    gemm_bt<D2, DD, 2, 128><<<dim3(MM / 128, D2 / 128), 256, 0, stream>>>(
        h2, w1_bf, b1, nullptr, ffh, nullptr, nullptr);
    gemm_bt<DD, D2, 3, 64><<<dim3(MM / 128, DD / 64), 256, 0, stream>>>(
        ffh, w2_bf, b2, xbuf, nullptr, out, nullptr);
}

// Round 8
// 283.837 us; speedup vs baseline: 1.0384x; 1.0288x over previous
//
#include <hip/hip_runtime.h>
#include <cstdint>

// ---------------------------------------------------------------------------
// SelfAttentionBlock: LN1 -> QKV -> MHA -> proj(+res) -> LN2 -> FFN(+res)
// B=8 N=2048 D=384 H=6 DK=64.  bf16 MFMA for all matmuls, fp32 LN/softmax/
// GELU/residuals.  Verified MFMA layouts (16x16x32 / shape family):
//   A[m=lane&15][k=(lane>>4)*8+j]  B[k=(lane>>4)*8+j][n=lane&15]
//   C/D[row=(lane>>4)*4+r][col=lane&15]
// 16x16x16 (_1k): A[m=lane&15][k=(lane>>4)*4+i], C/D same shape family.
// Round 16 = Round 15 resubmitted (R15 bench died to an infra flake:
// "container failed twice", no dispatches ran).  Content unchanged:
// R9-R14 established that NO schedule restructure moves attn (7 variants,
// 98-101us) or the GEMMs (3 variants, totals 290-295) -- implicit
// inter-block wave overlap already covers the barrier drains (m114).
// So: REVERT attn + GEMMs to best-measured versions (R8 attn 98.2us,
// R8 GEMMs) and fuse coords + transpose + LN1 into ONE pre_kernel --
// one read of the input slab instead of two, two fewer launches.
// ---------------------------------------------------------------------------

typedef __bf16 bf16;
typedef __bf16 bf16x8 __attribute__((ext_vector_type(8)));
typedef __bf16 bf16x4 __attribute__((ext_vector_type(4)));
typedef short s16x4 __attribute__((ext_vector_type(4)));
typedef float floatx4 __attribute__((ext_vector_type(4)));
typedef uint32_t __attribute__((address_space(1))) gu32;
typedef uint32_t __attribute__((address_space(3))) lu32;

#define NN 2048
#define DD 384
#define HH 6
#define DK 64
#define BB 8
#define MM (BB * NN)   // 16384 rows
#define D3 (3 * DD)    // 1152
#define D2 (2 * DD)    // 768
#define CH (3 + DD)    // 387 output channels
#define LP 72          // K-tile LDS row stride: 36 dwords -> 4-bank rotation/row
#define LPV 136        // V-tile LDS row stride: 68 dwords -> 4-bank rotation/row

// 0.125 * log2(e): folded into stored Q so softmax is p = exp2(q.k)
#define QSCALE 0.18033688011112042f

static __device__ __forceinline__ s16x4 as_s16x4(bf16x4 v) {
    union { bf16x4 b; s16x4 s; } u; u.b = v; return u.s;
}

// ---------------- small utility kernels ----------------

// all four weight casts in one launch
__global__ void cast_all_kernel(const float* __restrict__ w_qkv, const float* __restrict__ w_o,
                                const float* __restrict__ w1, const float* __restrict__ w2,
                                bf16* __restrict__ o_qkv, bf16* __restrict__ o_o,
                                bf16* __restrict__ o_w1, bf16* __restrict__ o_w2) {
    int i = blockIdx.x * 256 + threadIdx.x;   // total 1179648
    if (i < 442368) o_qkv[i] = (bf16)w_qkv[i];
    else if (i < 589824) o_o[i - 442368] = (bf16)w_o[i - 442368];
    else if (i < 884736) o_w1[i - 589824] = (bf16)w1[i - 589824];
    else o_w2[i - 884736] = (bf16)w2[i - 884736];
}

// fused: coords passthrough + (B,3+D,N)->(B,N,D) transpose + LN1.
// One block per (b, 32 points): LDS-stage the 384x32 fp32 slab (coalesced
// row reads), LN across D per point, write feats fp32 + h1 bf16 + coords.
__global__ __launch_bounds__(256) void pre_kernel(const float* __restrict__ pts,
                                                  const float* __restrict__ g,
                                                  const float* __restrict__ bta,
                                                  float* __restrict__ feats,
                                                  bf16* __restrict__ h1,
                                                  float* __restrict__ out) {
    __shared__ float T[32][385];               // [n][d], stride 385 -> conflict-free
    const int b = blockIdx.y, n0 = blockIdx.x * 32;
    const int t = threadIdx.x;
    const float* src = pts + (size_t)b * CH * NN;

    // coords rows 0..2 passthrough (96 floats/block)
    if (t < 96) {
        const int r = t >> 5, n = t & 31;
        out[((size_t)b * CH + r) * NN + n0 + n] = src[(size_t)r * NN + n0 + n];
    }

    // stage the feature slab: lane n = t&31 (coalesced 128B per row-pair)
    const int n = t & 31, d0 = t >> 5;         // 8 d-rows per pass
#pragma unroll
    for (int p = 0; p < 48; ++p) {
        const int d = p * 8 + d0;
        T[n][d] = src[(size_t)(3 + d) * NN + n0 + n];
    }
    __syncthreads();

    // LN per point: wave w handles rows w*8 .. w*8+7
    const int wave = t >> 6, lane = t & 63;
#pragma unroll
    for (int i = 0; i < 8; ++i) {
        const int rn = wave * 8 + i;
        float v[6], s = 0.f, sq = 0.f;
#pragma unroll
        for (int j = 0; j < 6; ++j) { v[j] = T[rn][lane + j * 64]; s += v[j]; sq += v[j] * v[j]; }
#pragma unroll
        for (int o = 1; o < 64; o <<= 1) { s += __shfl_xor(s, o); sq += __shfl_xor(sq, o); }
        const float mu = s * (1.f / DD);
        const float var = sq * (1.f / DD) - mu * mu;
        const float rs = rsqrtf(var + 1e-5f);
        float* fr = feats + ((size_t)b * NN + n0 + rn) * DD;
        bf16* hr = h1 + ((size_t)b * NN + n0 + rn) * DD;
#pragma unroll
        for (int j = 0; j < 6; ++j) {
            const int d = lane + j * 64;
            fr[d] = v[j];
            hr[d] = (bf16)((v[j] - mu) * rs * g[d] + bta[d]);
        }
    }
}

// rows of 384, one wave per row, fp32 in -> bf16 out (used for LN2)
__global__ __launch_bounds__(256) void ln_kernel(const float* __restrict__ x,
                                                 const float* __restrict__ g,
                                                 const float* __restrict__ bta,
                                                 bf16* __restrict__ out) {
    int wave = threadIdx.x >> 6, lane = threadIdx.x & 63;
    int row = blockIdx.x * 4 + wave;
    const float* xr = x + (size_t)row * DD;
    float v[6], s = 0.f, sq = 0.f;
#pragma unroll
    for (int i = 0; i < 6; ++i) { v[i] = xr[lane + i * 64]; s += v[i]; sq += v[i] * v[i]; }
#pragma unroll
    for (int o = 1; o < 64; o <<= 1) { s += __shfl_xor(s, o); sq += __shfl_xor(sq, o); }
    float mu = s * (1.f / DD);
    float var = sq * (1.f / DD) - mu * mu;
    float rs = rsqrtf(var + 1e-5f);
    bf16* orow = out + (size_t)row * DD;
#pragma unroll
    for (int i = 0; i < 6; ++i) {
        int d = lane + i * 64;
        orow[d] = (bf16)((v[i] - mu) * rs * g[d] + bta[d]);
    }
}

// ---------------- GEMM: C[M,NC] = A[M,K] * W[NC,K]^T, fused epilogues ----------------
// Tile: 128 rows x TN cols.  TN=128: 4 waves 2x2 of 64x64 (MI=4).
//                            TN=64 : 4 waves stacked, 32x64 each (MI=2).
// MODE 0: QKV  -> bf16 qkv (Q cols pre-scaled by QSCALE), V transposed to vt
// MODE 1: proj -> fp32 x = C + bias + res
// MODE 2: FF1  -> bf16 gelu(C + bias)
// MODE 3: FF2  -> fp32 out[(b,3+c,n)] = C + bias + res   (final transposed store)
template <int NC, int K, int MODE, int TN>
__global__ __launch_bounds__(256, 2)
void gemm_bt(const bf16* __restrict__ A, const bf16* __restrict__ W,
             const float* __restrict__ bias, const float* __restrict__ res,
             bf16* __restrict__ obf, float* __restrict__ of32, bf16* __restrict__ vt) {
    constexpr int MI = (TN == 128) ? 4 : 2;
    __shared__ bf16 As[128 * 32];
    __shared__ bf16 Ws[TN * 32];
    const int t = threadIdx.x;
    const int wave = t >> 6, lane = t & 63;
    const int m0 = blockIdx.x * 128, n0 = blockIdx.y * TN;
    const int wm = (TN == 128) ? (wave >> 1) * 64 : wave * 32;
    const int wn = (TN == 128) ? (wave & 1) * 64 : 0;
    const int lr = lane & 15, quad = lane >> 4;
    const int sr = t >> 2, sc = (t & 3) * 8;

    floatx4 acc[MI][4];
#pragma unroll
    for (int mi = 0; mi < MI; ++mi)
#pragma unroll
        for (int ni = 0; ni < 4; ++ni) {
            floatx4 z = {0.f, 0.f, 0.f, 0.f};
            acc[mi][ni] = z;
        }

    for (int k0 = 0; k0 < K; k0 += 32) {
        __syncthreads();
        // async global->LDS staging, 16B/lane; LDS offset == 16*t (lane*16-contiguous)
#pragma unroll
        for (int i = 0; i < 2; ++i) {
            const int r = i * 64 + sr;
            __builtin_amdgcn_global_load_lds(
                (const gu32*)&A[(size_t)(m0 + r) * K + k0 + sc],
                (lu32*)&As[r * 32 + sc], 16, 0, 0);
        }
#pragma unroll
        for (int i = 0; i < TN / 64; ++i) {
            const int r = i * 64 + sr;
            __builtin_amdgcn_global_load_lds(
                (const gu32*)&W[(size_t)(n0 + r) * K + k0 + sc],
                (lu32*)&Ws[r * 32 + sc], 16, 0, 0);
        }
        __syncthreads();
        bf16x8 af[MI], bfr[4];
#pragma unroll
        for (int mi = 0; mi < MI; ++mi)
            af[mi] = *(const bf16x8*)&As[(wm + mi * 16 + lr) * 32 + quad * 8];
#pragma unroll
        for (int ni = 0; ni < 4; ++ni)
            bfr[ni] = *(const bf16x8*)&Ws[(wn + ni * 16 + lr) * 32 + quad * 8];
#pragma unroll
        for (int mi = 0; mi < MI; ++mi)
#pragma unroll
            for (int ni = 0; ni < 4; ++ni)
                acc[mi][ni] = __builtin_amdgcn_mfma_f32_16x16x32_bf16(af[mi], bfr[ni], acc[mi][ni], 0, 0, 0);
    }

#pragma unroll
    for (int mi = 0; mi < MI; ++mi) {
#pragma unroll
        for (int ni = 0; ni < 4; ++ni) {
            const int r0 = m0 + wm + mi * 16 + quad * 4;  // 4 consecutive rows r0..r0+3
            const int c = n0 + wn + ni * 16 + lr;
            floatx4 v = acc[mi][ni];
            if constexpr (MODE == 0) {
                const int cb = n0 + wn + ni * 16;  // wave-uniform tile col base
                if (cb >= 2 * DD) {
                    // V: store transposed vt[b][h][dk][n], 4 consecutive n -> 8B store
                    const int hh = (c - 2 * DD) >> 6, dk = (c - 2 * DD) & 63;
                    const int b = r0 >> 11, n = r0 & (NN - 1);
                    bf16x4 pk;
#pragma unroll
                    for (int r = 0; r < 4; ++r) pk[r] = (bf16)v[r];
                    *(bf16x4*)&vt[((size_t)(b * HH + hh) * DK + dk) * NN + n] = pk;
                } else {
                    // Q columns (cb < DD) carry the softmax scale; K unscaled.
                    const float sc_q = (cb < DD) ? QSCALE : 1.0f;
#pragma unroll
                    for (int r = 0; r < 4; ++r) obf[(size_t)(r0 + r) * NC + c] = (bf16)(v[r] * sc_q);
                }
            } else if constexpr (MODE == 1) {
#pragma unroll
                for (int r = 0; r < 4; ++r)
                    of32[(size_t)(r0 + r) * NC + c] = v[r] + bias[c] + res[(size_t)(r0 + r) * NC + c];
            } else if constexpr (MODE == 2) {
#pragma unroll
                for (int r = 0; r < 4; ++r) {
                    float u = v[r] + bias[c];
                    obf[(size_t)(r0 + r) * NC + c] = (bf16)(0.5f * u * (1.f + erff(u * 0.70710678118f)));
                }
            } else {  // MODE 3: final residual + transposed store into output
                const int b = r0 >> 11, n = r0 & (NN - 1);
                float o4[4];
#pragma unroll
                for (int r = 0; r < 4; ++r)
                    o4[r] = v[r] + bias[c] + res[(size_t)(r0 + r) * DD + c];
                float4 val = make_float4(o4[0], o4[1], o4[2], o4[3]);
                *(float4*)&of32[((size_t)b * CH + 3 + c) * NN + n] = val;
            }
        }
    }
}

// ---------------- flash attention (best-measured R8 structure) -------------
// grid (N/128, B*H), 256 threads = 4 waves; wave owns 32 Q rows (frags in
// registers); K/V j-tiles of 128 (LDS-staged, padded strides); no-max
// streaming softmax via S^T; P in registers (16x16x16 PV).  2 barriers/tile,
// 16 tiles.
__global__ __launch_bounds__(256, 3)
void attn_kernel(const bf16* __restrict__ qkv, const bf16* __restrict__ vt,
                 bf16* __restrict__ ctx) {
    __shared__ bf16 Ks[128 * LP];       // K tile [j][d], j=0..127
    __shared__ bf16 Vs[64 * LPV];       // V^T tile [d][j], d=0..63, j=0..127
    const int t = threadIdx.x, wave = t >> 6, lane = t & 63;
    const int lr = lane & 15, quad = lane >> 4;
    const int bh = blockIdx.y, b = bh / HH, h = bh % HH;
    const int q0 = blockIdx.x * 128 + wave * 32;       // this wave's 32 Q rows
    const bf16* qbase = qkv + (size_t)b * NN * D3 + h * DK;          // Q cols (pre-scaled)
    const bf16* kbase = qbase + DD;                                   // K cols
    const bf16* vbase = vt + (size_t)bh * DK * NN;

    // Q frags: wave-private, j-invariant -> registers (used as B-operand)
    bf16x8 aq[2][2];
#pragma unroll
    for (int mi = 0; mi < 2; ++mi)
#pragma unroll
        for (int ks = 0; ks < 2; ++ks)
            aq[mi][ks] = *(const bf16x8*)&qbase[(size_t)(q0 + mi * 16 + lr) * D3 +
                                                ks * 32 + quad * 8];

    // ones B-fragment (K=16) for the denominator MFMA
    bf16x4 ones4;
#pragma unroll
    for (int i = 0; i < 4; ++i) ones4[i] = (bf16)1.0f;
    const s16x4 ones_s = as_s16x4(ones4);

    floatx4 o[2][4], ol[2];
#pragma unroll
    for (int mi = 0; mi < 2; ++mi) {
        floatx4 z = {0.f, 0.f, 0.f, 0.f};
        ol[mi] = z;
#pragma unroll
        for (int nd = 0; nd < 4; ++nd) o[mi][nd] = z;
    }

    for (int j0 = 0; j0 < NN; j0 += 128) {
        __syncthreads();
        {   // stage K tile: 128 rows x 64 cols (rows of 64 cols, 8 lanes/row)
            const int rr = t >> 3, cc = (t & 7) * 8;
#pragma unroll
            for (int i = 0; i < 4; ++i) {
                const int j = i * 32 + rr;
                *(bf16x8*)&Ks[j * LP + cc] =
                    *(const bf16x8*)&kbase[(size_t)(j0 + j) * D3 + cc];
            }
            // stage V^T tile: 64 rows (d) x 128 cols (j), 16 lanes/row
            const int rr2 = t >> 4, cc2 = (t & 15) * 8;
#pragma unroll
            for (int i = 0; i < 4; ++i) {
                const int d = i * 16 + rr2;
                *(bf16x8*)&Vs[d * LPV + cc2] =
                    *(const bf16x8*)&vbase[(size_t)d * NN + j0 + cc2];
            }
        }
        __syncthreads();

        // S^T = K * Q^T (operand swap).  C-layout: lane holds
        // j = nj*16+quad*4+{0..3}, q = mi*16+lr.
        floatx4 s[2][8];
#pragma unroll
        for (int mi = 0; mi < 2; ++mi)
#pragma unroll
            for (int nj = 0; nj < 8; ++nj) {
                floatx4 z = {0.f, 0.f, 0.f, 0.f};
                s[mi][nj] = z;
            }
#pragma unroll
        for (int ks = 0; ks < 2; ++ks)
#pragma unroll
            for (int nj = 0; nj < 8; ++nj) {
                bf16x8 bk = *(const bf16x8*)&Ks[(nj * 16 + lr) * LP + ks * 32 + quad * 8];
#pragma unroll
                for (int mi = 0; mi < 2; ++mi)
                    s[mi][nj] = __builtin_amdgcn_mfma_f32_16x16x32_bf16(bk, aq[mi][ks],
                                                                        s[mi][nj], 0, 0, 0);
            }

        // p = exp2(s) (scale folded into Q; bounded scores, shift-invariant).
        // Lane's (q=mi*16+lr, j=nj*16+quad*4+r) values are EXACTLY the
        // 16x16x16 A-fragment A[m=lr][k=quad*4+r] for PV step nj -> no LDS.
#pragma unroll
        for (int nj = 0; nj < 8; ++nj) {
            s16x4 ap[2];
#pragma unroll
            for (int mi = 0; mi < 2; ++mi) {
                bf16x4 pk;
#pragma unroll
                for (int r = 0; r < 4; ++r) pk[r] = (bf16)exp2f(s[mi][nj][r]);
                ap[mi] = as_s16x4(pk);
            }
            // O += P V (K=16 slice) ; l += P * ones
#pragma unroll
            for (int nd = 0; nd < 4; ++nd) {
                s16x4 bv = as_s16x4(*(const bf16x4*)&Vs[(nd * 16 + lr) * LPV +
                                                        nj * 16 + quad * 4]);
#pragma unroll
                for (int mi = 0; mi < 2; ++mi)
                    o[mi][nd] = __builtin_amdgcn_mfma_f32_16x16x16bf16_1k(ap[mi], bv,
                                                                          o[mi][nd], 0, 0, 0);
            }
#pragma unroll
            for (int mi = 0; mi < 2; ++mi)
                ol[mi] = __builtin_amdgcn_mfma_f32_16x16x16bf16_1k(ap[mi], ones_s, ol[mi], 0, 0, 0);
        }
    }

    // finalize: ctx[b,n, h*64+d] = o/l  (bf16); l rows match o rows.
#pragma unroll
    for (int mi = 0; mi < 2; ++mi)
#pragma unroll
        for (int r = 0; r < 4; ++r) {
            const int n = q0 + mi * 16 + quad * 4 + r;
            const float inv = 1.0f / ol[mi][r];
#pragma unroll
            for (int nd = 0; nd < 4; ++nd) {
                const int d = h * DK + nd * 16 + lr;
                ctx[(size_t)(b * NN + n) * DD + d] = (bf16)(o[mi][nd][r] * inv);
            }
        }
}

// ---------------- host launch ----------------

extern "C" void kernel_launch(void* const* d_in, const int* in_sizes, int n_in,
                              void* d_out, int out_size, void* d_ws, size_t ws_size,
                              hipStream_t stream) {
    const float* points = (const float*)d_in[0];
    const float* ln1_g = (const float*)d_in[1];
    const float* ln1_b = (const float*)d_in[2];
    const float* w_qkv = (const float*)d_in[3];
    const float* w_o   = (const float*)d_in[4];
    const float* b_o   = (const float*)d_in[5];
    const float* ln2_g = (const float*)d_in[6];
    const float* ln2_b = (const float*)d_in[7];
    const float* w1    = (const float*)d_in[8];
    const float* b1    = (const float*)d_in[9];
    const float* w2    = (const float*)d_in[10];
    const float* b2    = (const float*)d_in[11];
    float* out = (float*)d_out;

    char* ws = (char*)d_ws;
    size_t off = 0;
    auto alloc = [&](size_t bytes) -> void* {
        void* p = ws + off;
        off += (bytes + 255) & ~(size_t)255;
        return p;
    };
    float* feats = (float*)alloc((size_t)MM * DD * 4);
    float* xbuf  = (float*)alloc((size_t)MM * DD * 4);
    bf16* h1     = (bf16*)alloc((size_t)MM * DD * 2);
    bf16* h2     = (bf16*)alloc((size_t)MM * DD * 2);
    bf16* qkvb   = (bf16*)alloc((size_t)MM * D3 * 2);
    bf16* vtb    = (bf16*)alloc((size_t)BB * HH * DK * NN * 2);
    bf16* ctx    = (bf16*)alloc((size_t)MM * DD * 2);
    bf16* ffh    = (bf16*)alloc((size_t)MM * D2 * 2);
    bf16* wqkv_bf = (bf16*)alloc((size_t)D3 * DD * 2);
    bf16* wo_bf   = (bf16*)alloc((size_t)DD * DD * 2);
    bf16* w1_bf   = (bf16*)alloc((size_t)D2 * DD * 2);
    bf16* w2_bf   = (bf16*)alloc((size_t)DD * D2 * 2);

    cast_all_kernel<<<1179648 / 256, 256, 0, stream>>>(w_qkv, w_o, w1, w2,
                                                       wqkv_bf, wo_bf, w1_bf, w2_bf);
    pre_kernel<<<dim3(NN / 32, BB), 256, 0, stream>>>(points, ln1_g, ln1_b,
                                                      feats, h1, out);
    gemm_bt<D3, DD, 0, 128><<<dim3(MM / 128, D3 / 128), 256, 0, stream>>>(
        h1, wqkv_bf, nullptr, nullptr, qkvb, nullptr, vtb);
    attn_kernel<<<dim3(NN / 128, BB * HH), 256, 0, stream>>>(qkvb, vtb, ctx);
    gemm_bt<DD, DD, 1, 64><<<dim3(MM / 128, DD / 64), 256, 0, stream>>>(
        ctx, wo_bf, b_o, feats, nullptr, xbuf, nullptr);
    ln_kernel<<<MM / 4, 256, 0, stream>>>(xbuf, ln2_g, ln2_b, h2);
    gemm_bt<D2, DD, 2, 128><<<dim3(MM / 128, D2 / 128), 256, 0, stream>>>(
        h2, w1_bf, b1, nullptr, ffh, nullptr, nullptr);
    gemm_bt<DD, D2, 3, 64><<<dim3(MM / 128, DD / 64), 256, 0, stream>>>(
        ffh, w2_bf, b2, xbuf, nullptr, out, nullptr);
}

// Round 9
// 276.564 us; speedup vs baseline: 1.0657x; 1.0263x over previous
//
#include <hip/hip_runtime.h>
#include <cstdint>

// ---------------------------------------------------------------------------
// SelfAttentionBlock: LN1 -> QKV -> MHA -> proj(+res) -> LN2 -> FFN(+res)
// B=8 N=2048 D=384 H=6 DK=64.  bf16 MFMA for all matmuls, fp32 LN/softmax/
// GELU/residuals.  Verified MFMA layouts (16x16x32 / shape family):
//   A[m=lane&15][k=(lane>>4)*8+j]  B[k=(lane>>4)*8+j][n=lane&15]
//   C/D[row=(lane>>4)*4+r][col=lane&15]
// 16x16x16 (_1k): A[m=lane&15][k=(lane>>4)*4+i], C/D same shape family.
// Round 17: R16 confirmed fusion works (283.8, pred 280-284) and attn is
// restored to its best signature.  Remaining slack: 4 GEMMs ~160us for
// 38.7 GFLOP (~240 TF).  Schedule variants were null (m114), but the
// work-per-barrier ratio never changed.  This round: BK 32 -> 64 (half the
// barriers/drains, 2x MFMA per staged tile, the m93 ladder lever), with the
// attn-validated 16B-granule XOR swizzle (pre-swizzled global source +
// hoisted read offsets) to kill the [row][64]-stride bank conflict that
// linear BK=64 LDS would introduce (m201).  Epilogues, attn, pre, ln2
// unchanged from R16.
// ---------------------------------------------------------------------------

typedef __bf16 bf16;
typedef __bf16 bf16x8 __attribute__((ext_vector_type(8)));
typedef __bf16 bf16x4 __attribute__((ext_vector_type(4)));
typedef short s16x4 __attribute__((ext_vector_type(4)));
typedef float floatx4 __attribute__((ext_vector_type(4)));
typedef uint32_t __attribute__((address_space(1))) gu32;
typedef uint32_t __attribute__((address_space(3))) lu32;

#define NN 2048
#define DD 384
#define HH 6
#define DK 64
#define BB 8
#define MM (BB * NN)   // 16384 rows
#define D3 (3 * DD)    // 1152
#define D2 (2 * DD)    // 768
#define CH (3 + DD)    // 387 output channels
#define LP 72          // K-tile LDS row stride: 36 dwords -> 4-bank rotation/row
#define LPV 136        // V-tile LDS row stride: 68 dwords -> 4-bank rotation/row

// 0.125 * log2(e): folded into stored Q so softmax is p = exp2(q.k)
#define QSCALE 0.18033688011112042f

static __device__ __forceinline__ s16x4 as_s16x4(bf16x4 v) {
    union { bf16x4 b; s16x4 s; } u; u.b = v; return u.s;
}

// ---------------- small utility kernels ----------------

// all four weight casts in one launch
__global__ void cast_all_kernel(const float* __restrict__ w_qkv, const float* __restrict__ w_o,
                                const float* __restrict__ w1, const float* __restrict__ w2,
                                bf16* __restrict__ o_qkv, bf16* __restrict__ o_o,
                                bf16* __restrict__ o_w1, bf16* __restrict__ o_w2) {
    int i = blockIdx.x * 256 + threadIdx.x;   // total 1179648
    if (i < 442368) o_qkv[i] = (bf16)w_qkv[i];
    else if (i < 589824) o_o[i - 442368] = (bf16)w_o[i - 442368];
    else if (i < 884736) o_w1[i - 589824] = (bf16)w1[i - 589824];
    else o_w2[i - 884736] = (bf16)w2[i - 884736];
}

// fused: coords passthrough + (B,3+D,N)->(B,N,D) transpose + LN1.
// One block per (b, 32 points): LDS-stage the 384x32 fp32 slab (coalesced
// row reads), LN across D per point, write feats fp32 + h1 bf16 + coords.
__global__ __launch_bounds__(256) void pre_kernel(const float* __restrict__ pts,
                                                  const float* __restrict__ g,
                                                  const float* __restrict__ bta,
                                                  float* __restrict__ feats,
                                                  bf16* __restrict__ h1,
                                                  float* __restrict__ out) {
    __shared__ float T[32][385];               // [n][d], stride 385 -> conflict-free
    const int b = blockIdx.y, n0 = blockIdx.x * 32;
    const int t = threadIdx.x;
    const float* src = pts + (size_t)b * CH * NN;

    // coords rows 0..2 passthrough (96 floats/block)
    if (t < 96) {
        const int r = t >> 5, n = t & 31;
        out[((size_t)b * CH + r) * NN + n0 + n] = src[(size_t)r * NN + n0 + n];
    }

    // stage the feature slab: lane n = t&31 (coalesced 128B per row-pair)
    const int n = t & 31, d0 = t >> 5;         // 8 d-rows per pass
#pragma unroll
    for (int p = 0; p < 48; ++p) {
        const int d = p * 8 + d0;
        T[n][d] = src[(size_t)(3 + d) * NN + n0 + n];
    }
    __syncthreads();

    // LN per point: wave w handles rows w*8 .. w*8+7
    const int wave = t >> 6, lane = t & 63;
#pragma unroll
    for (int i = 0; i < 8; ++i) {
        const int rn = wave * 8 + i;
        float v[6], s = 0.f, sq = 0.f;
#pragma unroll
        for (int j = 0; j < 6; ++j) { v[j] = T[rn][lane + j * 64]; s += v[j]; sq += v[j] * v[j]; }
#pragma unroll
        for (int o = 1; o < 64; o <<= 1) { s += __shfl_xor(s, o); sq += __shfl_xor(sq, o); }
        const float mu = s * (1.f / DD);
        const float var = sq * (1.f / DD) - mu * mu;
        const float rs = rsqrtf(var + 1e-5f);
        float* fr = feats + ((size_t)b * NN + n0 + rn) * DD;
        bf16* hr = h1 + ((size_t)b * NN + n0 + rn) * DD;
#pragma unroll
        for (int j = 0; j < 6; ++j) {
            const int d = lane + j * 64;
            fr[d] = v[j];
            hr[d] = (bf16)((v[j] - mu) * rs * g[d] + bta[d]);
        }
    }
}

// rows of 384, one wave per row, fp32 in -> bf16 out (used for LN2)
__global__ __launch_bounds__(256) void ln_kernel(const float* __restrict__ x,
                                                 const float* __restrict__ g,
                                                 const float* __restrict__ bta,
                                                 bf16* __restrict__ out) {
    int wave = threadIdx.x >> 6, lane = threadIdx.x & 63;
    int row = blockIdx.x * 4 + wave;
    const float* xr = x + (size_t)row * DD;
    float v[6], s = 0.f, sq = 0.f;
#pragma unroll
    for (int i = 0; i < 6; ++i) { v[i] = xr[lane + i * 64]; s += v[i]; sq += v[i] * v[i]; }
#pragma unroll
    for (int o = 1; o < 64; o <<= 1) { s += __shfl_xor(s, o); sq += __shfl_xor(sq, o); }
    float mu = s * (1.f / DD);
    float var = sq * (1.f / DD) - mu * mu;
    float rs = rsqrtf(var + 1e-5f);
    bf16* orow = out + (size_t)row * DD;
#pragma unroll
    for (int i = 0; i < 6; ++i) {
        int d = lane + i * 64;
        orow[d] = (bf16)((v[i] - mu) * rs * g[d] + bta[d]);
    }
}

// ---------------- GEMM: C[M,NC] = A[M,K] * W[NC,K]^T, fused epilogues ----------------
// Tile: 128 rows x TN cols.  TN=128: 4 waves 2x2 of 64x64 (MI=4).
//                            TN=64 : 4 waves stacked, 32x64 each (MI=2).
// Round 17 k-loop: BK=64 (half the barriers vs BK=32, 32 MFMA per staged
// tile per wave).  LDS rows are 128B -> linear layout would be a 16-way
// bank conflict on ds_read_b128 (m201); fixed with the attn-validated
// 16B-granule XOR swizzle: DMA writes linear LDS (dst = t*16B), the GLOBAL
// source address carries the swizzle (chunk ^= row&7), reads use hoisted
// per-lane offsets with the matching XOR.
// MODE 0: QKV  -> bf16 qkv (Q cols pre-scaled by QSCALE), V transposed to vt
// MODE 1: proj -> fp32 x = C + bias + res
// MODE 2: FF1  -> bf16 gelu(C + bias)
// MODE 3: FF2  -> fp32 out[(b,3+c,n)] = C + bias + res   (final transposed store)
template <int NC, int K, int MODE, int TN>
__global__ __launch_bounds__(256, 2)
void gemm_bt(const bf16* __restrict__ A, const bf16* __restrict__ W,
             const float* __restrict__ bias, const float* __restrict__ res,
             bf16* __restrict__ obf, float* __restrict__ of32, bf16* __restrict__ vt) {
    constexpr int MI = (TN == 128) ? 4 : 2;
    __shared__ bf16 As[128 * 64];       // 16 KB, row stride 128B (swizzled)
    __shared__ bf16 Ws[TN * 64];        // 16/8 KB
    const int t = threadIdx.x;
    const int wave = t >> 6, lane = t & 63;
    const int m0 = blockIdx.x * 128, n0 = blockIdx.y * TN;
    const int wm = (TN == 128) ? (wave >> 1) * 64 : wave * 32;
    const int wn = (TN == 128) ? (wave & 1) * 64 : 0;
    const int lr = lane & 15, quad = lane >> 4, lx = lane & 7;

    // DMA staging geometry (attn pattern): thread t fills phys 16B chunk
    // (t&7) of row (t>>3)+32i; content = logical chunk (t&7)^(row&7), i.e.
    // the swizzle rides on the GLOBAL source address.  32 rows per issue.
    const int srow = t >> 3;                       // 0..31
    const int schunk = ((t & 7) ^ (srow & 7)) * 8; // bf16 elems

    // hoisted read offsets (bytes): logical (row, chunk c) -> phys c^(row&7)
    // row&7 == lr&7 == lx for all frag rows (wm/wn/mi*16 are mult. of 8).
    const int ca0 = ((quad) ^ lx) * 16;        // kk=0: chunks 0..3
    const int ca1 = ((4 + quad) ^ lx) * 16;    // kk=1: chunks 4..7
    const int arow = (wm + lr) * 128;          // + mi*2048
    const int brow = (wn + lr) * 128;          // + ni*2048

    floatx4 acc[MI][4];
#pragma unroll
    for (int mi = 0; mi < MI; ++mi)
#pragma unroll
        for (int ni = 0; ni < 4; ++ni) {
            floatx4 z = {0.f, 0.f, 0.f, 0.f};
            acc[mi][ni] = z;
        }

    for (int k0 = 0; k0 < K; k0 += 64) {
        __syncthreads();
        // A tile: 128 rows x 64 cols, 4 issues of 32 rows
#pragma unroll
        for (int i = 0; i < 4; ++i) {
            const int r = i * 32 + srow;
            __builtin_amdgcn_global_load_lds(
                (const gu32*)&A[(size_t)(m0 + r) * K + k0 + schunk],
                (lu32*)&As[i * 2048 + t * 8], 16, 0, 0);
        }
        // W tile: TN rows x 64 cols
#pragma unroll
        for (int i = 0; i < TN / 32; ++i) {
            const int r = i * 32 + srow;
            __builtin_amdgcn_global_load_lds(
                (const gu32*)&W[(size_t)(n0 + r) * K + k0 + schunk],
                (lu32*)&Ws[i * 2048 + t * 8], 16, 0, 0);
        }
        __syncthreads();

        const char* ab = (const char*)As;
        const char* wb = (const char*)Ws;
#pragma unroll
        for (int kk = 0; kk < 2; ++kk) {
            const int ca = kk ? ca1 : ca0;
            bf16x8 af[MI], bfr[4];
#pragma unroll
            for (int mi = 0; mi < MI; ++mi)
                af[mi] = *(const bf16x8*)(ab + arow + mi * 2048 + ca);
#pragma unroll
            for (int ni = 0; ni < 4; ++ni)
                bfr[ni] = *(const bf16x8*)(wb + brow + ni * 2048 + ca);
#pragma unroll
            for (int mi = 0; mi < MI; ++mi)
#pragma unroll
                for (int ni = 0; ni < 4; ++ni)
                    acc[mi][ni] = __builtin_amdgcn_mfma_f32_16x16x32_bf16(af[mi], bfr[ni], acc[mi][ni], 0, 0, 0);
        }
    }

#pragma unroll
    for (int mi = 0; mi < MI; ++mi) {
#pragma unroll
        for (int ni = 0; ni < 4; ++ni) {
            const int r0 = m0 + wm + mi * 16 + quad * 4;  // 4 consecutive rows r0..r0+3
            const int c = n0 + wn + ni * 16 + lr;
            floatx4 v = acc[mi][ni];
            if constexpr (MODE == 0) {
                const int cb = n0 + wn + ni * 16;  // wave-uniform tile col base
                if (cb >= 2 * DD) {
                    // V: store transposed vt[b][h][dk][n], 4 consecutive n -> 8B store
                    const int hh = (c - 2 * DD) >> 6, dk = (c - 2 * DD) & 63;
                    const int b = r0 >> 11, n = r0 & (NN - 1);
                    bf16x4 pk;
#pragma unroll
                    for (int r = 0; r < 4; ++r) pk[r] = (bf16)v[r];
                    *(bf16x4*)&vt[((size_t)(b * HH + hh) * DK + dk) * NN + n] = pk;
                } else {
                    // Q columns (cb < DD) carry the softmax scale; K unscaled.
                    const float sc_q = (cb < DD) ? QSCALE : 1.0f;
#pragma unroll
                    for (int r = 0; r < 4; ++r) obf[(size_t)(r0 + r) * NC + c] = (bf16)(v[r] * sc_q);
                }
            } else if constexpr (MODE == 1) {
#pragma unroll
                for (int r = 0; r < 4; ++r)
                    of32[(size_t)(r0 + r) * NC + c] = v[r] + bias[c] + res[(size_t)(r0 + r) * NC + c];
            } else if constexpr (MODE == 2) {
#pragma unroll
                for (int r = 0; r < 4; ++r) {
                    float u = v[r] + bias[c];
                    obf[(size_t)(r0 + r) * NC + c] = (bf16)(0.5f * u * (1.f + erff(u * 0.70710678118f)));
                }
            } else {  // MODE 3: final residual + transposed store into output
                const int b = r0 >> 11, n = r0 & (NN - 1);
                float o4[4];
#pragma unroll
                for (int r = 0; r < 4; ++r)
                    o4[r] = v[r] + bias[c] + res[(size_t)(r0 + r) * DD + c];
                float4 val = make_float4(o4[0], o4[1], o4[2], o4[3]);
                *(float4*)&of32[((size_t)b * CH + 3 + c) * NN + n] = val;
            }
        }
    }
}

// ---------------- flash attention (best-measured R8 structure) -------------
// grid (N/128, B*H), 256 threads = 4 waves; wave owns 32 Q rows (frags in
// registers); K/V j-tiles of 128 (LDS-staged, padded strides); no-max
// streaming softmax via S^T; P in registers (16x16x16 PV).  2 barriers/tile,
// 16 tiles.
__global__ __launch_bounds__(256, 3)
void attn_kernel(const bf16* __restrict__ qkv, const bf16* __restrict__ vt,
                 bf16* __restrict__ ctx) {
    __shared__ bf16 Ks[128 * LP];       // K tile [j][d], j=0..127
    __shared__ bf16 Vs[64 * LPV];       // V^T tile [d][j], d=0..63, j=0..127
    const int t = threadIdx.x, wave = t >> 6, lane = t & 63;
    const int lr = lane & 15, quad = lane >> 4;
    const int bh = blockIdx.y, b = bh / HH, h = bh % HH;
    const int q0 = blockIdx.x * 128 + wave * 32;       // this wave's 32 Q rows
    const bf16* qbase = qkv + (size_t)b * NN * D3 + h * DK;          // Q cols (pre-scaled)
    const bf16* kbase = qbase + DD;                                   // K cols
    const bf16* vbase = vt + (size_t)bh * DK * NN;

    // Q frags: wave-private, j-invariant -> registers (used as B-operand)
    bf16x8 aq[2][2];
#pragma unroll
    for (int mi = 0; mi < 2; ++mi)
#pragma unroll
        for (int ks = 0; ks < 2; ++ks)
            aq[mi][ks] = *(const bf16x8*)&qbase[(size_t)(q0 + mi * 16 + lr) * D3 +
                                                ks * 32 + quad * 8];

    // ones B-fragment (K=16) for the denominator MFMA
    bf16x4 ones4;
#pragma unroll
    for (int i = 0; i < 4; ++i) ones4[i] = (bf16)1.0f;
    const s16x4 ones_s = as_s16x4(ones4);

    floatx4 o[2][4], ol[2];
#pragma unroll
    for (int mi = 0; mi < 2; ++mi) {
        floatx4 z = {0.f, 0.f, 0.f, 0.f};
        ol[mi] = z;
#pragma unroll
        for (int nd = 0; nd < 4; ++nd) o[mi][nd] = z;
    }

    for (int j0 = 0; j0 < NN; j0 += 128) {
        __syncthreads();
        {   // stage K tile: 128 rows x 64 cols (rows of 64 cols, 8 lanes/row)
            const int rr = t >> 3, cc = (t & 7) * 8;
#pragma unroll
            for (int i = 0; i < 4; ++i) {
                const int j = i * 32 + rr;
                *(bf16x8*)&Ks[j * LP + cc] =
                    *(const bf16x8*)&kbase[(size_t)(j0 + j) * D3 + cc];
            }
            // stage V^T tile: 64 rows (d) x 128 cols (j), 16 lanes/row
            const int rr2 = t >> 4, cc2 = (t & 15) * 8;
#pragma unroll
            for (int i = 0; i < 4; ++i) {
                const int d = i * 16 + rr2;
                *(bf16x8*)&Vs[d * LPV + cc2] =
                    *(const bf16x8*)&vbase[(size_t)d * NN + j0 + cc2];
            }
        }
        __syncthreads();

        // S^T = K * Q^T (operand swap).  C-layout: lane holds
        // j = nj*16+quad*4+{0..3}, q = mi*16+lr.
        floatx4 s[2][8];
#pragma unroll
        for (int mi = 0; mi < 2; ++mi)
#pragma unroll
            for (int nj = 0; nj < 8; ++nj) {
                floatx4 z = {0.f, 0.f, 0.f, 0.f};
                s[mi][nj] = z;
            }
#pragma unroll
        for (int ks = 0; ks < 2; ++ks)
#pragma unroll
            for (int nj = 0; nj < 8; ++nj) {
                bf16x8 bk = *(const bf16x8*)&Ks[(nj * 16 + lr) * LP + ks * 32 + quad * 8];
#pragma unroll
                for (int mi = 0; mi < 2; ++mi)
                    s[mi][nj] = __builtin_amdgcn_mfma_f32_16x16x32_bf16(bk, aq[mi][ks],
                                                                        s[mi][nj], 0, 0, 0);
            }

        // p = exp2(s) (scale folded into Q; bounded scores, shift-invariant).
        // Lane's (q=mi*16+lr, j=nj*16+quad*4+r) values are EXACTLY the
        // 16x16x16 A-fragment A[m=lr][k=quad*4+r] for PV step nj -> no LDS.
#pragma unroll
        for (int nj = 0; nj < 8; ++nj) {
            s16x4 ap[2];
#pragma unroll
            for (int mi = 0; mi < 2; ++mi) {
                bf16x4 pk;
#pragma unroll
                for (int r = 0; r < 4; ++r) pk[r] = (bf16)exp2f(s[mi][nj][r]);
                ap[mi] = as_s16x4(pk);
            }
            // O += P V (K=16 slice) ; l += P * ones
#pragma unroll
            for (int nd = 0; nd < 4; ++nd) {
                s16x4 bv = as_s16x4(*(const bf16x4*)&Vs[(nd * 16 + lr) * LPV +
                                                        nj * 16 + quad * 4]);
#pragma unroll
                for (int mi = 0; mi < 2; ++mi)
                    o[mi][nd] = __builtin_amdgcn_mfma_f32_16x16x16bf16_1k(ap[mi], bv,
                                                                          o[mi][nd], 0, 0, 0);
            }
#pragma unroll
            for (int mi = 0; mi < 2; ++mi)
                ol[mi] = __builtin_amdgcn_mfma_f32_16x16x16bf16_1k(ap[mi], ones_s, ol[mi], 0, 0, 0);
        }
    }

    // finalize: ctx[b,n, h*64+d] = o/l  (bf16); l rows match o rows.
#pragma unroll
    for (int mi = 0; mi < 2; ++mi)
#pragma unroll
        for (int r = 0; r < 4; ++r) {
            const int n = q0 + mi * 16 + quad * 4 + r;
            const float inv = 1.0f / ol[mi][r];
#pragma unroll
            for (int nd = 0; nd < 4; ++nd) {
                const int d = h * DK + nd * 16 + lr;
                ctx[(size_t)(b * NN + n) * DD + d] = (bf16)(o[mi][nd][r] * inv);
            }
        }
}

// ---------------- host launch ----------------

extern "C" void kernel_launch(void* const* d_in, const int* in_sizes, int n_in,
                              void* d_out, int out_size, void* d_ws, size_t ws_size,
                              hipStream_t stream) {
    const float* points = (const float*)d_in[0];
    const float* ln1_g = (const float*)d_in[1];
    const float* ln1_b = (const float*)d_in[2];
    const float* w_qkv = (const float*)d_in[3];
    const float* w_o   = (const float*)d_in[4];
    const float* b_o   = (const float*)d_in[5];
    const float* ln2_g = (const float*)d_in[6];
    const float* ln2_b = (const float*)d_in[7];
    const float* w1    = (const float*)d_in[8];
    const float* b1    = (const float*)d_in[9];
    const float* w2    = (const float*)d_in[10];
    const float* b2    = (const float*)d_in[11];
    float* out = (float*)d_out;

    char* ws = (char*)d_ws;
    size_t off = 0;
    auto alloc = [&](size_t bytes) -> void* {
        void* p = ws + off;
        off += (bytes + 255) & ~(size_t)255;
        return p;
    };
    float* feats = (float*)alloc((size_t)MM * DD * 4);
    float* xbuf  = (float*)alloc((size_t)MM * DD * 4);
    bf16* h1     = (bf16*)alloc((size_t)MM * DD * 2);
    bf16* h2     = (bf16*)alloc((size_t)MM * DD * 2);
    bf16* qkvb   = (bf16*)alloc((size_t)MM * D3 * 2);
    bf16* vtb    = (bf16*)alloc((size_t)BB * HH * DK * NN * 2);
    bf16* ctx    = (bf16*)alloc((size_t)MM * DD * 2);
    bf16* ffh    = (bf16*)alloc((size_t)MM * D2 * 2);
    bf16* wqkv_bf = (bf16*)alloc((size_t)D3 * DD * 2);
    bf16* wo_bf   = (bf16*)alloc((size_t)DD * DD * 2);
    bf16* w1_bf   = (bf16*)alloc((size_t)D2 * DD * 2);
    bf16* w2_bf   = (bf16*)alloc((size_t)DD * D2 * 2);

    cast_all_kernel<<<1179648 / 256, 256, 0, stream>>>(w_qkv, w_o, w1, w2,
                                                       wqkv_bf, wo_bf, w1_bf, w2_bf);
    pre_kernel<<<dim3(NN / 32, BB), 256, 0, stream>>>(points, ln1_g, ln1_b,
                                                      feats, h1, out);
    gemm_bt<D3, DD, 0, 128><<<dim3(MM / 128, D3 / 128), 256, 0, stream>>>(
        h1, wqkv_bf, nullptr, nullptr, qkvb, nullptr, vtb);
    attn_kernel<<<dim3(NN / 128, BB * HH), 256, 0, stream>>>(qkvb, vtb, ctx);
    gemm_bt<DD, DD, 1, 64><<<dim3(MM / 128, DD / 64), 256, 0, stream>>>(
        ctx, wo_bf, b_o, feats, nullptr, xbuf, nullptr);
    ln_kernel<<<MM / 4, 256, 0, stream>>>(xbuf, ln2_g, ln2_b, h2);
    gemm_bt<D2, DD, 2, 128><<<dim3(MM / 128, D2 / 128), 256, 0, stream>>>(
        h2, w1_bf, b1, nullptr, ffh, nullptr, nullptr);
    gemm_bt<DD, D2, 3, 64><<<dim3(MM / 128, DD / 64), 256, 0, stream>>>(
        ffh, w2_bf, b2, xbuf, nullptr, out, nullptr);
}

// Round 10
// 264.174 us; speedup vs baseline: 1.1157x; 1.0469x over previous
//
#include <hip/hip_runtime.h>
#include <cstdint>

// ---------------------------------------------------------------------------
// SelfAttentionBlock: LN1 -> QKV -> MHA -> proj(+res) -> LN2 -> FFN(+res)
// B=8 N=2048 D=384 H=6 DK=64.  bf16 MFMA for all matmuls, fp32 LN/softmax/
// GELU/residuals.  Verified MFMA layouts (16x16x32 / shape family):
//   A[m=lane&15][k=(lane>>4)*8+j]  B[k=(lane>>4)*8+j][n=lane&15]
//   C/D[row=(lane>>4)*4+r][col=lane&15]
// 16x16x16 (_1k): A[m=lane&15][k=(lane>>4)*4+i], C/D same shape family.
// Round 18: R17 (BK=64) confirmed +7us -- work-per-barrier is the GEMM
// lever.  This round removes more WORK with zero numeric risk:
// (1) feats buffer deleted -- proj's residual == points[b][3+c][n]
//     bit-exact, staged transposed into reused LDS in the epilogue
//     (25MB of HBM writes gone from pre);
// (2) cast_all merged into pre_kernel (one fewer dispatch).
// attn (best R8 structure), GEMM k-loop (BK=64 + XOR swizzle) unchanged.
// ---------------------------------------------------------------------------

typedef __bf16 bf16;
typedef __bf16 bf16x8 __attribute__((ext_vector_type(8)));
typedef __bf16 bf16x4 __attribute__((ext_vector_type(4)));
typedef short s16x4 __attribute__((ext_vector_type(4)));
typedef float floatx4 __attribute__((ext_vector_type(4)));
typedef uint32_t __attribute__((address_space(1))) gu32;
typedef uint32_t __attribute__((address_space(3))) lu32;

#define NN 2048
#define DD 384
#define HH 6
#define DK 64
#define BB 8
#define MM (BB * NN)   // 16384 rows
#define D3 (3 * DD)    // 1152
#define D2 (2 * DD)    // 768
#define CH (3 + DD)    // 387 output channels
#define LP 72          // K-tile LDS row stride: 36 dwords -> 4-bank rotation/row
#define LPV 136        // V-tile LDS row stride: 68 dwords -> 4-bank rotation/row

#define PREBLK (BB * NN / 32)          // 512 pre blocks
#define CASTBLK 576                    // 576 cast blocks x 2048 elems

// 0.125 * log2(e): folded into stored Q so softmax is p = exp2(q.k)
#define QSCALE 0.18033688011112042f

static __device__ __forceinline__ s16x4 as_s16x4(bf16x4 v) {
    union { bf16x4 b; s16x4 s; } u; u.b = v; return u.s;
}

// ---------------- fused pre kernel ----------------
// blocks [0, PREBLK): coords passthrough + (B,3+D,N)->(B,N,D) transpose + LN1
//   (h1 bf16 out; NO feats buffer -- proj reads the residual from points).
// blocks [PREBLK, PREBLK+CASTBLK): all four weight casts (8 elems/thread).
__global__ __launch_bounds__(256) void pre_kernel(
        const float* __restrict__ pts, const float* __restrict__ g,
        const float* __restrict__ bta, bf16* __restrict__ h1,
        float* __restrict__ out,
        const float* __restrict__ w_qkv, const float* __restrict__ w_o,
        const float* __restrict__ w1, const float* __restrict__ w2,
        bf16* __restrict__ o_qkv, bf16* __restrict__ o_o,
        bf16* __restrict__ o_w1, bf16* __restrict__ o_w2) {
    __shared__ float T[32][385];               // [n][d], stride 385 -> conflict-free
    const int bid = blockIdx.x, t = threadIdx.x;

    if (bid >= PREBLK) {                       // ---- weight-cast blocks ----
        const int base = (bid - PREBLK) * 2048 + t * 8;
#pragma unroll
        for (int i = 0; i < 8; ++i) {
            const int idx = base + i;          // < 1179648 by construction
            if (idx < 442368) o_qkv[idx] = (bf16)w_qkv[idx];
            else if (idx < 589824) o_o[idx - 442368] = (bf16)w_o[idx - 442368];
            else if (idx < 884736) o_w1[idx - 589824] = (bf16)w1[idx - 589824];
            else o_w2[idx - 884736] = (bf16)w2[idx - 884736];
        }
        return;
    }

    const int b = bid >> 6, n0 = (bid & 63) * 32;
    const float* src = pts + (size_t)b * CH * NN;

    // coords rows 0..2 passthrough (96 floats/block)
    if (t < 96) {
        const int r = t >> 5, n = t & 31;
        out[((size_t)b * CH + r) * NN + n0 + n] = src[(size_t)r * NN + n0 + n];
    }

    // stage the feature slab: lane n = t&31 (coalesced 128B per row-pair)
    const int n = t & 31, d0 = t >> 5;         // 8 d-rows per pass
#pragma unroll
    for (int p = 0; p < 48; ++p) {
        const int d = p * 8 + d0;
        T[n][d] = src[(size_t)(3 + d) * NN + n0 + n];
    }
    __syncthreads();

    // LN per point: wave w handles rows w*8 .. w*8+7
    const int wave = t >> 6, lane = t & 63;
#pragma unroll
    for (int i = 0; i < 8; ++i) {
        const int rn = wave * 8 + i;
        float v[6], s = 0.f, sq = 0.f;
#pragma unroll
        for (int j = 0; j < 6; ++j) { v[j] = T[rn][lane + j * 64]; s += v[j]; sq += v[j] * v[j]; }
#pragma unroll
        for (int o = 1; o < 64; o <<= 1) { s += __shfl_xor(s, o); sq += __shfl_xor(sq, o); }
        const float mu = s * (1.f / DD);
        const float var = sq * (1.f / DD) - mu * mu;
        const float rs = rsqrtf(var + 1e-5f);
        bf16* hr = h1 + ((size_t)b * NN + n0 + rn) * DD;
#pragma unroll
        for (int j = 0; j < 6; ++j) {
            const int d = lane + j * 64;
            hr[d] = (bf16)((v[j] - mu) * rs * g[d] + bta[d]);
        }
    }
}

// rows of 384, one wave per row, fp32 in -> bf16 out (used for LN2)
__global__ __launch_bounds__(256) void ln_kernel(const float* __restrict__ x,
                                                 const float* __restrict__ g,
                                                 const float* __restrict__ bta,
                                                 bf16* __restrict__ out) {
    int wave = threadIdx.x >> 6, lane = threadIdx.x & 63;
    int row = blockIdx.x * 4 + wave;
    const float* xr = x + (size_t)row * DD;
    float v[6], s = 0.f, sq = 0.f;
#pragma unroll
    for (int i = 0; i < 6; ++i) { v[i] = xr[lane + i * 64]; s += v[i]; sq += v[i] * v[i]; }
#pragma unroll
    for (int o = 1; o < 64; o <<= 1) { s += __shfl_xor(s, o); sq += __shfl_xor(sq, o); }
    float mu = s * (1.f / DD);
    float var = sq * (1.f / DD) - mu * mu;
    float rs = rsqrtf(var + 1e-5f);
    bf16* orow = out + (size_t)row * DD;
#pragma unroll
    for (int i = 0; i < 6; ++i) {
        int d = lane + i * 64;
        orow[d] = (bf16)((v[i] - mu) * rs * g[d] + bta[d]);
    }
}

// ---------------- GEMM: C[M,NC] = A[M,K] * W[NC,K]^T, fused epilogues ----------------
// Tile: 128 rows x TN cols.  TN=128: 4 waves 2x2 of 64x64 (MI=4).
//                            TN=64 : 4 waves stacked, 32x64 each (MI=2).
// BK=64 k-loop (R17): DMA writes linear LDS, GLOBAL source address carries
// the 16B-granule XOR swizzle (chunk ^= row&7), reads use hoisted per-lane
// offsets with the matching XOR (no bank conflicts at 128B row stride).
// MODE 0: QKV  -> bf16 qkv (Q cols pre-scaled by QSCALE), V transposed to vt
// MODE 1: proj -> fp32 x = C + bias + res; res read TRANSPOSED from points
//         (staged 64c x 128n fp32 into reused smem in the epilogue)
// MODE 2: FF1  -> bf16 gelu(C + bias)
// MODE 3: FF2  -> fp32 out[(b,3+c,n)] = C + bias + res   (final transposed store)
template <int NC, int K, int MODE, int TN>
__global__ __launch_bounds__(256, 2)
void gemm_bt(const bf16* __restrict__ A, const bf16* __restrict__ W,
             const float* __restrict__ bias, const float* __restrict__ res,
             bf16* __restrict__ obf, float* __restrict__ of32, bf16* __restrict__ vt) {
    constexpr int MI = (TN == 128) ? 4 : 2;
    constexpr int SMEM_KLOOP = (128 * 64 + TN * 64) * 2;   // As + Ws bytes
    constexpr int SMEM_RT = 64 * 132 * 4;                  // MODE1 res tile
    constexpr int SMEM_BYTES =
        (MODE == 1 && SMEM_RT > SMEM_KLOOP) ? SMEM_RT : SMEM_KLOOP;
    __shared__ __align__(16) char smem[SMEM_BYTES];
    bf16* As = (bf16*)smem;                    // 128 x 64, swizzled chunks
    bf16* Ws = (bf16*)(smem + 128 * 64 * 2);   // TN x 64
    const int t = threadIdx.x;
    const int wave = t >> 6, lane = t & 63;
    const int m0 = blockIdx.x * 128, n0 = blockIdx.y * TN;
    const int wm = (TN == 128) ? (wave >> 1) * 64 : wave * 32;
    const int wn = (TN == 128) ? (wave & 1) * 64 : 0;
    const int lr = lane & 15, quad = lane >> 4, lx = lane & 7;

    // DMA staging geometry: thread t fills phys 16B chunk (t&7) of row
    // (t>>3)+32i; content = logical chunk (t&7)^(row&7) via global source.
    const int srow = t >> 3;                       // 0..31
    const int schunk = ((t & 7) ^ (srow & 7)) * 8; // bf16 elems

    // hoisted read offsets (bytes): logical (row, chunk c) -> phys c^(row&7)
    const int ca0 = ((quad) ^ lx) * 16;        // kk=0: chunks 0..3
    const int ca1 = ((4 + quad) ^ lx) * 16;    // kk=1: chunks 4..7
    const int arow = (wm + lr) * 128;          // + mi*2048
    const int brow = (wn + lr) * 128;          // + ni*2048

    floatx4 acc[MI][4];
#pragma unroll
    for (int mi = 0; mi < MI; ++mi)
#pragma unroll
        for (int ni = 0; ni < 4; ++ni) {
            floatx4 z = {0.f, 0.f, 0.f, 0.f};
            acc[mi][ni] = z;
        }

    for (int k0 = 0; k0 < K; k0 += 64) {
        __syncthreads();
        // A tile: 128 rows x 64 cols, 4 issues of 32 rows
#pragma unroll
        for (int i = 0; i < 4; ++i) {
            const int r = i * 32 + srow;
            __builtin_amdgcn_global_load_lds(
                (const gu32*)&A[(size_t)(m0 + r) * K + k0 + schunk],
                (lu32*)&As[i * 2048 + t * 8], 16, 0, 0);
        }
        // W tile: TN rows x 64 cols
#pragma unroll
        for (int i = 0; i < TN / 32; ++i) {
            const int r = i * 32 + srow;
            __builtin_amdgcn_global_load_lds(
                (const gu32*)&W[(size_t)(n0 + r) * K + k0 + schunk],
                (lu32*)&Ws[i * 2048 + t * 8], 16, 0, 0);
        }
        __syncthreads();

        const char* ab = (const char*)As;
        const char* wb = (const char*)Ws;
#pragma unroll
        for (int kk = 0; kk < 2; ++kk) {
            const int ca = kk ? ca1 : ca0;
            bf16x8 af[MI], bfr[4];
#pragma unroll
            for (int mi = 0; mi < MI; ++mi)
                af[mi] = *(const bf16x8*)(ab + arow + mi * 2048 + ca);
#pragma unroll
            for (int ni = 0; ni < 4; ++ni)
                bfr[ni] = *(const bf16x8*)(wb + brow + ni * 2048 + ca);
#pragma unroll
            for (int mi = 0; mi < MI; ++mi)
#pragma unroll
                for (int ni = 0; ni < 4; ++ni)
                    acc[mi][ni] = __builtin_amdgcn_mfma_f32_16x16x32_bf16(af[mi], bfr[ni], acc[mi][ni], 0, 0, 0);
        }
    }

    // MODE 1: stage the residual tile (points, transposed) into reused smem.
    // Rt[cc][nn] = points[b][3+n0+cc][m0n+nn], cc in [0,64), nn in [0,128).
    float* Rt = (float*)smem;
    if constexpr (MODE == 1) {
        __syncthreads();                       // everyone done with As/Ws
        const int bb = m0 >> 11, m0n = m0 & (NN - 1);
        const int cc = t >> 2, l4 = (t & 3) * 32;
        const float* prow = res + ((size_t)bb * CH + 3 + n0 + cc) * NN + m0n + l4;
#pragma unroll
        for (int i = 0; i < 8; ++i) {
            float4 vv = *(const float4*)&prow[i * 4];
            *(float4*)&Rt[cc * 132 + l4 + i * 4] = vv;
        }
        __syncthreads();
    }

#pragma unroll
    for (int mi = 0; mi < MI; ++mi) {
#pragma unroll
        for (int ni = 0; ni < 4; ++ni) {
            const int r0 = m0 + wm + mi * 16 + quad * 4;  // 4 consecutive rows r0..r0+3
            const int c = n0 + wn + ni * 16 + lr;
            floatx4 v = acc[mi][ni];
            if constexpr (MODE == 0) {
                const int cb = n0 + wn + ni * 16;  // wave-uniform tile col base
                if (cb >= 2 * DD) {
                    // V: store transposed vt[b][h][dk][n], 4 consecutive n -> 8B store
                    const int hh = (c - 2 * DD) >> 6, dk = (c - 2 * DD) & 63;
                    const int b = r0 >> 11, n = r0 & (NN - 1);
                    bf16x4 pk;
#pragma unroll
                    for (int r = 0; r < 4; ++r) pk[r] = (bf16)v[r];
                    *(bf16x4*)&vt[((size_t)(b * HH + hh) * DK + dk) * NN + n] = pk;
                } else {
                    // Q columns (cb < DD) carry the softmax scale; K unscaled.
                    const float sc_q = (cb < DD) ? QSCALE : 1.0f;
#pragma unroll
                    for (int r = 0; r < 4; ++r) obf[(size_t)(r0 + r) * NC + c] = (bf16)(v[r] * sc_q);
                }
            } else if constexpr (MODE == 1) {
                const int rr = (wn + ni * 16 + lr) * 132;      // Rt row (= c-n0)
                const int nnb = wm + mi * 16 + quad * 4;       // Rt col base
#pragma unroll
                for (int r = 0; r < 4; ++r)
                    of32[(size_t)(r0 + r) * NC + c] = v[r] + bias[c] + Rt[rr + nnb + r];
            } else if constexpr (MODE == 2) {
#pragma unroll
                for (int r = 0; r < 4; ++r) {
                    float u = v[r] + bias[c];
                    obf[(size_t)(r0 + r) * NC + c] = (bf16)(0.5f * u * (1.f + erff(u * 0.70710678118f)));
                }
            } else {  // MODE 3: final residual + transposed store into output
                const int b = r0 >> 11, n = r0 & (NN - 1);
                float o4[4];
#pragma unroll
                for (int r = 0; r < 4; ++r)
                    o4[r] = v[r] + bias[c] + res[(size_t)(r0 + r) * DD + c];
                float4 val = make_float4(o4[0], o4[1], o4[2], o4[3]);
                *(float4*)&of32[((size_t)b * CH + 3 + c) * NN + n] = val;
            }
        }
    }
}

// ---------------- flash attention (best-measured R8 structure) -------------
// grid (N/128, B*H), 256 threads = 4 waves; wave owns 32 Q rows (frags in
// registers); K/V j-tiles of 128 (LDS-staged, padded strides); no-max
// streaming softmax via S^T; P in registers (16x16x16 PV).  2 barriers/tile,
// 16 tiles.
__global__ __launch_bounds__(256, 3)
void attn_kernel(const bf16* __restrict__ qkv, const bf16* __restrict__ vt,
                 bf16* __restrict__ ctx) {
    __shared__ bf16 Ks[128 * LP];       // K tile [j][d], j=0..127
    __shared__ bf16 Vs[64 * LPV];       // V^T tile [d][j], d=0..63, j=0..127
    const int t = threadIdx.x, wave = t >> 6, lane = t & 63;
    const int lr = lane & 15, quad = lane >> 4;
    const int bh = blockIdx.y, b = bh / HH, h = bh % HH;
    const int q0 = blockIdx.x * 128 + wave * 32;       // this wave's 32 Q rows
    const bf16* qbase = qkv + (size_t)b * NN * D3 + h * DK;          // Q cols (pre-scaled)
    const bf16* kbase = qbase + DD;                                   // K cols
    const bf16* vbase = vt + (size_t)bh * DK * NN;

    // Q frags: wave-private, j-invariant -> registers (used as B-operand)
    bf16x8 aq[2][2];
#pragma unroll
    for (int mi = 0; mi < 2; ++mi)
#pragma unroll
        for (int ks = 0; ks < 2; ++ks)
            aq[mi][ks] = *(const bf16x8*)&qbase[(size_t)(q0 + mi * 16 + lr) * D3 +
                                                ks * 32 + quad * 8];

    // ones B-fragment (K=16) for the denominator MFMA
    bf16x4 ones4;
#pragma unroll
    for (int i = 0; i < 4; ++i) ones4[i] = (bf16)1.0f;
    const s16x4 ones_s = as_s16x4(ones4);

    floatx4 o[2][4], ol[2];
#pragma unroll
    for (int mi = 0; mi < 2; ++mi) {
        floatx4 z = {0.f, 0.f, 0.f, 0.f};
        ol[mi] = z;
#pragma unroll
        for (int nd = 0; nd < 4; ++nd) o[mi][nd] = z;
    }

    for (int j0 = 0; j0 < NN; j0 += 128) {
        __syncthreads();
        {   // stage K tile: 128 rows x 64 cols (rows of 64 cols, 8 lanes/row)
            const int rr = t >> 3, cc = (t & 7) * 8;
#pragma unroll
            for (int i = 0; i < 4; ++i) {
                const int j = i * 32 + rr;
                *(bf16x8*)&Ks[j * LP + cc] =
                    *(const bf16x8*)&kbase[(size_t)(j0 + j) * D3 + cc];
            }
            // stage V^T tile: 64 rows (d) x 128 cols (j), 16 lanes/row
            const int rr2 = t >> 4, cc2 = (t & 15) * 8;
#pragma unroll
            for (int i = 0; i < 4; ++i) {
                const int d = i * 16 + rr2;
                *(bf16x8*)&Vs[d * LPV + cc2] =
                    *(const bf16x8*)&vbase[(size_t)d * NN + j0 + cc2];
            }
        }
        __syncthreads();

        // S^T = K * Q^T (operand swap).  C-layout: lane holds
        // j = nj*16+quad*4+{0..3}, q = mi*16+lr.
        floatx4 s[2][8];
#pragma unroll
        for (int mi = 0; mi < 2; ++mi)
#pragma unroll
            for (int nj = 0; nj < 8; ++nj) {
                floatx4 z = {0.f, 0.f, 0.f, 0.f};
                s[mi][nj] = z;
            }
#pragma unroll
        for (int ks = 0; ks < 2; ++ks)
#pragma unroll
            for (int nj = 0; nj < 8; ++nj) {
                bf16x8 bk = *(const bf16x8*)&Ks[(nj * 16 + lr) * LP + ks * 32 + quad * 8];
#pragma unroll
                for (int mi = 0; mi < 2; ++mi)
                    s[mi][nj] = __builtin_amdgcn_mfma_f32_16x16x32_bf16(bk, aq[mi][ks],
                                                                        s[mi][nj], 0, 0, 0);
            }

        // p = exp2(s) (scale folded into Q; bounded scores, shift-invariant).
        // Lane's (q=mi*16+lr, j=nj*16+quad*4+r) values are EXACTLY the
        // 16x16x16 A-fragment A[m=lr][k=quad*4+r] for PV step nj -> no LDS.
#pragma unroll
        for (int nj = 0; nj < 8; ++nj) {
            s16x4 ap[2];
#pragma unroll
            for (int mi = 0; mi < 2; ++mi) {
                bf16x4 pk;
#pragma unroll
                for (int r = 0; r < 4; ++r) pk[r] = (bf16)exp2f(s[mi][nj][r]);
                ap[mi] = as_s16x4(pk);
            }
            // O += P V (K=16 slice) ; l += P * ones
#pragma unroll
            for (int nd = 0; nd < 4; ++nd) {
                s16x4 bv = as_s16x4(*(const bf16x4*)&Vs[(nd * 16 + lr) * LPV +
                                                        nj * 16 + quad * 4]);
#pragma unroll
                for (int mi = 0; mi < 2; ++mi)
                    o[mi][nd] = __builtin_amdgcn_mfma_f32_16x16x16bf16_1k(ap[mi], bv,
                                                                          o[mi][nd], 0, 0, 0);
            }
#pragma unroll
            for (int mi = 0; mi < 2; ++mi)
                ol[mi] = __builtin_amdgcn_mfma_f32_16x16x16bf16_1k(ap[mi], ones_s, ol[mi], 0, 0, 0);
        }
    }

    // finalize: ctx[b,n, h*64+d] = o/l  (bf16); l rows match o rows.
#pragma unroll
    for (int mi = 0; mi < 2; ++mi)
#pragma unroll
        for (int r = 0; r < 4; ++r) {
            const int n = q0 + mi * 16 + quad * 4 + r;
            const float inv = 1.0f / ol[mi][r];
#pragma unroll
            for (int nd = 0; nd < 4; ++nd) {
                const int d = h * DK + nd * 16 + lr;
                ctx[(size_t)(b * NN + n) * DD + d] = (bf16)(o[mi][nd][r] * inv);
            }
        }
}

// ---------------- host launch ----------------

extern "C" void kernel_launch(void* const* d_in, const int* in_sizes, int n_in,
                              void* d_out, int out_size, void* d_ws, size_t ws_size,
                              hipStream_t stream) {
    const float* points = (const float*)d_in[0];
    const float* ln1_g = (const float*)d_in[1];
    const float* ln1_b = (const float*)d_in[2];
    const float* w_qkv = (const float*)d_in[3];
    const float* w_o   = (const float*)d_in[4];
    const float* b_o   = (const float*)d_in[5];
    const float* ln2_g = (const float*)d_in[6];
    const float* ln2_b = (const float*)d_in[7];
    const float* w1    = (const float*)d_in[8];
    const float* b1    = (const float*)d_in[9];
    const float* w2    = (const float*)d_in[10];
    const float* b2    = (const float*)d_in[11];
    float* out = (float*)d_out;

    char* ws = (char*)d_ws;
    size_t off = 0;
    auto alloc = [&](size_t bytes) -> void* {
        void* p = ws + off;
        off += (bytes + 255) & ~(size_t)255;
        return p;
    };
    float* xbuf  = (float*)alloc((size_t)MM * DD * 4);
    bf16* h1     = (bf16*)alloc((size_t)MM * DD * 2);
    bf16* h2     = (bf16*)alloc((size_t)MM * DD * 2);
    bf16* qkvb   = (bf16*)alloc((size_t)MM * D3 * 2);
    bf16* vtb    = (bf16*)alloc((size_t)BB * HH * DK * NN * 2);
    bf16* ctx    = (bf16*)alloc((size_t)MM * DD * 2);
    bf16* ffh    = (bf16*)alloc((size_t)MM * D2 * 2);
    bf16* wqkv_bf = (bf16*)alloc((size_t)D3 * DD * 2);
    bf16* wo_bf   = (bf16*)alloc((size_t)DD * DD * 2);
    bf16* w1_bf   = (bf16*)alloc((size_t)D2 * DD * 2);
    bf16* w2_bf   = (bf16*)alloc((size_t)DD * D2 * 2);

    pre_kernel<<<PREBLK + CASTBLK, 256, 0, stream>>>(
        points, ln1_g, ln1_b, h1, out,
        w_qkv, w_o, w1, w2, wqkv_bf, wo_bf, w1_bf, w2_bf);
    gemm_bt<D3, DD, 0, 128><<<dim3(MM / 128, D3 / 128), 256, 0, stream>>>(
        h1, wqkv_bf, nullptr, nullptr, qkvb, nullptr, vtb);
    attn_kernel<<<dim3(NN / 128, BB * HH), 256, 0, stream>>>(qkvb, vtb, ctx);
    gemm_bt<DD, DD, 1, 64><<<dim3(MM / 128, DD / 64), 256, 0, stream>>>(
        ctx, wo_bf, b_o, points, nullptr, xbuf, nullptr);
    ln_kernel<<<MM / 4, 256, 0, stream>>>(xbuf, ln2_g, ln2_b, h2);
    gemm_bt<D2, DD, 2, 128><<<dim3(MM / 128, D2 / 128), 256, 0, stream>>>(
        h2, w1_bf, b1, nullptr, ffh, nullptr, nullptr);
    gemm_bt<DD, D2, 3, 64><<<dim3(MM / 128, DD / 64), 256, 0, stream>>>(
        ffh, w2_bf, b2, xbuf, nullptr, out, nullptr);
}